// Round 11
// baseline (93.797 us; speedup 1.0000x reference)
//
#include <hip/hip_runtime.h>

// 3 kernels:
//  k_dot (500 blk): V = h @ W_top (HBM floor ~10.5us), MA = bitmask(g)
//  k_mid (25 blk x 1024): redundant-per-block SH + Z + top-400 rank (cheap,
//        deterministic, identical across blocks), then wave-per-row dense
//        layer-0 2-hop -> complement CP0 + RSUM + SU. out[0:500] by block 0.
//  k_fin (1 blk x 1024): m0 + z1 (complement walks) + rank top-300 + hop1
//        (intersect-early-exit) + scalar cascade (complete-graph fast path,
//        with R10-verified general fallback). out[500:1500].
// ws (u32 words): V@0, IDXA@512, SELA@1024(32), RSUMo@1056, SUc@1568,
// SUo@2080, CP0@2592(8000), MA@10592(8000)

#define MS 16
struct P4 { const float* p[4]; };

__device__ __forceinline__ float bitselF(unsigned m, int k, float v) {
    int s = ((int)(m << (31 - k))) >> 31;
    return __int_as_float(s & __float_as_int(v));
}
__device__ __forceinline__ float fbfly(float v) {
#pragma unroll
    for (int o = 32; o; o >>= 1) v += __shfl_xor(v, o);
    return v;
}
__device__ __forceinline__ int ibfly(int v) {
#pragma unroll
    for (int o = 32; o; o >>= 1) v += __shfl_xor(v, o);
    return v;
}
__device__ __forceinline__ float sigm(float x) { return 1.f / (1.f + expf(-x)); }

// sparse bit-walk over a 16-word LDS row
__device__ __forceinline__ float pwalk16(const unsigned* __restrict__ row,
                                         const float* __restrict__ val) {
    float a = 0.f;
#pragma unroll
    for (int w = 0; w < 16; ++w) {
        unsigned m = row[w];
        while (m) {
            int b = __ffs((int)m) - 1;
            m &= m - 1;
            a += val[(w << 5) + b];
        }
    }
    return a;
}

// wave-cooperative stable rank over padded-512 LDS array (pads = -1),
// scalar stride-1 reads (conflict-free)
__device__ __forceinline__ int wrank(const float* __restrict__ sc, float my,
                                     int r, int lane) {
    int cnt = 0;
#pragma unroll
    for (int q = 0; q < 8; ++q) {
        int j = lane + 64 * q;
        float s = sc[j];
        cnt += (s > my) || (s == my && j < r);
    }
    return ibfly(cnt);
}

// K1: V[row] = dot(h[row,:], W_top); MA[row] = bitmask(g row).
__global__ __launch_bounds__(1024) void k_dot(const float* __restrict__ h,
        const float* __restrict__ Wt, const float* __restrict__ g,
        float* __restrict__ V, unsigned* __restrict__ MA) {
    int row = blockIdx.x, t = threadIdx.x;
    const float4* h4 = (const float4*)(h + (size_t)row * 32768);
    const float4* w4 = (const float4*)Wt;
    float acc = 0.f;
#pragma unroll
    for (int j = 0; j < 8; ++j) {
        float4 a = h4[t + 1024 * j], b = w4[t + 1024 * j];
        acc = fmaf(a.x, b.x, fmaf(a.y, b.y, fmaf(a.z, b.z, fmaf(a.w, b.w, acc))));
    }
    acc = fbfly(acc);
    __shared__ float red[16];
    if ((t & 63) == 0) red[t >> 6] = acc;
    __syncthreads();
    if (t == 0) {
        float s = 0.f;
        for (int i = 0; i < 16; ++i) s += red[i];
        V[row] = s;
    }
    if (t < 512) {
        float gv = (t < 500) ? g[row * 500 + t] : 0.f;
        unsigned long long bal = __ballot(gv != 0.f);
        if ((t & 63) == 0) {
            int w = t >> 6;
            MA[row * MS + 2 * w] = (unsigned)bal;
            MA[row * MS + 2 * w + 1] = (unsigned)(bal >> 32);
        }
    }
}

// K2: fused SH + Z + rank0 + layer-0 two-hop. 25 blocks x 1024 (16 waves).
__global__ __launch_bounds__(1024) void k_mid(const unsigned* __restrict__ MA,
        const float* __restrict__ V, const float* __restrict__ b_top,
        const float* __restrict__ Wp0, const float* __restrict__ bp0,
        const float* __restrict__ Wd0, float* __restrict__ out,
        int* __restrict__ IDXA, unsigned* __restrict__ SELA,
        unsigned* __restrict__ CP0, float* __restrict__ RSUMo,
        float* __restrict__ SUc, float* __restrict__ SUo) {
    __shared__ __align__(16) unsigned sMA[8000];
    __shared__ float sv[512], sh[512], sz[512];
    __shared__ int sIDX[512];
    __shared__ unsigned sSEL[16];
    __shared__ unsigned srow[16][16];
    int t = threadIdx.x, wid = t >> 6, lane = t & 63;
    for (int q = t; q < 2000; q += 1024)
        ((uint4*)sMA)[q] = ((const uint4*)MA)[q];
    if (t < 512) sv[t] = (t < 500) ? V[t] : 0.f;
    if (t < 16) sSEL[t] = 0u;
    __syncthreads();
    // SH = relu(MA . V + b_top), wave per row (rows wave-cyclic)
    for (int r = wid; r < 500; r += 16) {
        float acc = 0.f;
#pragma unroll
        for (int j = 0; j < 8; ++j) {
            unsigned m = sMA[r * MS + 2 * j + (lane >> 5)];
            acc += bitselF(m, lane & 31, sv[64 * j + lane]);
        }
        acc = fbfly(acc);
        if (lane == 0) sh[r] = fmaxf(acc + b_top[0], 0.f);
    }
    if (t >= 500 && t < 512) sh[t] = 0.f;
    __syncthreads();
    if (blockIdx.x == 0 && t < 500) out[t] = sh[t];
    // Z = relu((MA . SH)*Wp0 + bp0)  (sigmoid monotone: rank on z)
    for (int r = wid; r < 500; r += 16) {
        float acc = 0.f;
#pragma unroll
        for (int j = 0; j < 8; ++j) {
            unsigned m = sMA[r * MS + 2 * j + (lane >> 5)];
            acc += bitselF(m, lane & 31, sh[64 * j + lane]);
        }
        acc = fbfly(acc);
        if (lane == 0) sz[r] = fmaxf(acc * Wp0[0] + bp0[0], 0.f);
    }
    if (t >= 500 && t < 512) sz[t] = -1.f;
    __syncthreads();
    // stable top-400 rank (redundant per block, deterministic)
    for (int r = wid; r < 500; r += 16) {
        float my = sz[r];
        int cnt = wrank(sz, my, r, lane);
        if (lane == 0 && cnt < 400) {
            sIDX[cnt] = r;
            atomicOr(&sSEL[r >> 5], 1u << (r & 31));
        }
    }
    __syncthreads();
    if (blockIdx.x == 0) {
        if (t < 400) IDXA[t] = sIDX[t];
        if (t < 16) SELA[t] = sSEL[t];
        if (t >= 400 && t < 512) SUc[t] = 0.f;
    }
    // layer-0 two-hop: wave per compact row (25 blk x 16 waves = 400)
    int r4 = blockIdx.x * 16 + wid;
    int i = sIDX[r4];
    if (lane < 16) srow[wid][lane] = sMA[i * MS + lane];
    __syncthreads();
    int part = lane >> 4, w = lane & 15;
    unsigned acc = 0;
    for (int k = part; k < 500; k += 4) {
        unsigned mw = srow[wid][k >> 5];
        unsigned sel = (mw >> (k & 31)) & 1u;
        acc |= sMA[k * MS + w] & (0u - sel);
    }
    acc |= (unsigned)__shfl_xor((int)acc, 16);
    acc |= (unsigned)__shfl_xor((int)acc, 32);
    unsigned P = sSEL[w] & ~acc;  // complement within selection
    int pc = (lane < 16) ? __popc(P) : 0;
    pc = ibfly(pc);
    if (lane < 16) CP0[i * MS + lane] = P;
    if (lane == 0) {
        float rs = (float)(400 - pc);
        RSUMo[i] = rs;
        float su = sh[i] * sigm(sz[i]) * Wd0[r4] / rs;
        SUc[r4] = su;
        SUo[i] = su;
    }
}

// K3: m0 + z1 + rank1 + hop1 + layers 2-3. Single block x 1024.
__global__ __launch_bounds__(1024) void k_fin(const int* __restrict__ IDXA,
        const unsigned* __restrict__ SELAg, const unsigned* __restrict__ CP0g,
        const float* __restrict__ RSUMg, const float* __restrict__ SUcg,
        const float* __restrict__ SUog, P4 Wp, P4 bp, P4 Wd, P4 bd,
        float* __restrict__ out) {
    __shared__ __align__(16) unsigned sCP[8000];
    __shared__ float szC[512], svC[512], s2C[512];
    __shared__ float svO[512], s2O[512], shvO[512], sHSo[512], srsO[512];
    __shared__ int sIDXp[2][512];
    __shared__ unsigned sSELp[2][16];
    __shared__ float sS[8];
    __shared__ float stot0, stot1, stotS;
    __shared__ int sFlag;
    int t = threadIdx.x, wid = t >> 6, lane = t & 63;
    for (int q = t; q < 2000; q += 1024)
        ((uint4*)sCP)[q] = ((const uint4*)CP0g)[q];
    if (t < 512) {
        sIDXp[0][t] = (t < 400) ? IDXA[t] : 0;
        svC[t] = SUcg[t];  // 400..511 zero-padded by K2
    }
    if (t < 16) {
        sSELp[0][t] = SELAg[t];
        sSELp[1][t] = 0u;
    }
    if (t == 0) sFlag = 0;
    __syncthreads();
    if (t < 400) {
        int i = sIDXp[0][t];
        svO[i] = svC[t];
        srsO[i] = RSUMg[i];
    }
    __syncthreads();
    // tot0
    if (t < 64) {
        float p = 0.f;
#pragma unroll
        for (int j = 0; j < 8; ++j) p += svC[t * 8 + j];
        p = fbfly(p);
        if (t == 0) stot0 = p;
    }
    __syncthreads();
    // m0: h1 = relu(tot0 - complement + bd0)
    int i0 = 0;
    if (t < 400) {
        i0 = sIDXp[0][t];
        float corr = pwalk16(sCP + i0 * MS, svO);
        float h1 = fmaxf(stot0 - corr + bd.p[0][0], 0.f);
        out[500 + t] = h1;
        shvO[i0] = h1;
        float s2 = h1 / srsO[i0];
        s2C[t] = s2;
        s2O[i0] = s2;
    } else if (t < 512) {
        s2C[t] = 0.f;
    }
    __syncthreads();
    // tot1
    if (t < 64) {
        float p = 0.f;
#pragma unroll
        for (int j = 0; j < 8; ++j) p += s2C[t * 8 + j];
        p = fbfly(p);
        if (t == 0) stot1 = p;
    }
    __syncthreads();
    // z1
    if (t < 400) {
        float c2 = pwalk16(sCP + i0 * MS, s2O);
        szC[t] = fmaxf((stot1 - c2) * Wp.p[1][0] + bp.p[1][0], 0.f);
    } else if (t < 512) {
        szC[t] = -1.f;
    }
    __syncthreads();
    // rank: top-300 of 400 (compact tie-break)
    for (int r = wid; r < 400; r += 16) {
        float my = szC[r];
        int cnt = wrank(szC, my, r, lane);
        if (lane == 0 && cnt < 300) {
            int io = sIDXp[0][r];
            sIDXp[1][cnt] = io;
            sHSo[io] = shvO[io] * sigm(my);
            atomicOr(&sSELp[1][io >> 5], 1u << (io & 31));
        }
    }
    __syncthreads();
    // hop1: intersect of complements, early exit; flag if any row nonempty
    unsigned P[16];
    int inew = 0, pc = 0;
    float su_ = 0.f;
    if (t < 300) {
        inew = sIDXp[1][t];
#pragma unroll
        for (int w = 0; w < 16; ++w) P[w] = sSELp[1][w];
        bool alive = true;
        for (int w2 = 0; w2 < 16 && alive; ++w2) {
            unsigned nb = sSELp[0][w2] & ~sCP[inew * MS + w2];
            while (nb) {
                int b = __ffs((int)nb) - 1;
                nb &= nb - 1;
                const unsigned* cj = sCP + (w2 * 32 + b) * MS;
                unsigned orr = 0;
#pragma unroll
                for (int w = 0; w < 16; ++w) {
                    P[w] &= cj[w];
                    orr |= P[w];
                }
                if (!orr) { alive = false; break; }
            }
        }
#pragma unroll
        for (int w = 0; w < 16; ++w) pc += __popc(P[w]);
        if (pc > 0) atomicOr(&sFlag, 1);
        float rs = (float)(300 - pc);
        su_ = sHSo[inew] * Wd.p[1][t] / rs;
    }
    __syncthreads();
    if (t < 300) {
#pragma unroll
        for (int w = 0; w < 16; ++w) sCP[inew * MS + w] = P[w];
        srsO[inew] = (float)(300 - pc);
        svC[t] = su_;
        svO[inew] = su_;
    } else if (t < 512) {
        svC[t] = 0.f;
    }
    __syncthreads();
    if (sFlag == 0) {
        // ---- scalar fast path: layers 1-3 graphs are complete ----
        if (t < 64) {
            float p = 0.f;
#pragma unroll
            for (int j = 0; j < 8; ++j) p += svC[t * 8 + j];
            p = fbfly(p);
            if (t == 0) {
                float h2 = fmaxf(p + bd.p[1][0], 0.f);
                float z2 = fmaxf(h2 * Wp.p[2][0] + bp.p[2][0], 0.f);
                sS[0] = h2;
                sS[1] = h2 * sigm(z2);
            }
        }
        __syncthreads();
        float HS2 = sS[1];
        if (t < 512) s2C[t] = (t < 200) ? HS2 * Wd.p[2][t] / 200.f : 0.f;
        __syncthreads();
        if (t < 64) {
            float p = 0.f;
#pragma unroll
            for (int j = 0; j < 8; ++j) p += s2C[t * 8 + j];
            p = fbfly(p);
            if (t == 0) {
                float h3 = fmaxf(p + bd.p[2][0], 0.f);
                float z3 = fmaxf(h3 * Wp.p[3][0] + bp.p[3][0], 0.f);
                sS[2] = h3;
                sS[3] = h3 * sigm(z3);
            }
        }
        __syncthreads();
        float HS3 = sS[3];
        if (t < 512) s2C[t] = (t < 100) ? HS3 * Wd.p[3][t] / 100.f : 0.f;
        __syncthreads();
        if (t < 64) {
            float p = 0.f;
#pragma unroll
            for (int j = 0; j < 8; ++j) p += s2C[t * 8 + j];
            p = fbfly(p);
            if (t == 0) sS[4] = fmaxf(p + bd.p[3][0], 0.f);
        }
        __syncthreads();
        if (t < 300) out[900 + t] = sS[0];
        else if (t < 500) out[1200 + (t - 300)] = sS[2];
        else if (t < 600) out[1400 + (t - 500)] = sS[4];
        return;
    }
    // ---- general fallback (correct; not expected to execute) ----
    const int kks[3] = {300, 200, 100};
    const int kns[3] = {200, 100, 0};
    const int offs[3] = {900, 1200, 1400};
    for (int l = 1; l <= 3; ++l) {
        const int kk = kks[l - 1], knext = kns[l - 1], off = offs[l - 1];
        const int cur = l & 1, nxt = cur ^ 1;
        if (t < 64) {
            float p = 0.f;
#pragma unroll
            for (int j = 0; j < 8; ++j) p += svC[t * 8 + j];
            p = fbfly(p);
            if (t == 0) stotS = p;
        }
        __syncthreads();
        int i_ = 0;
        if (t < kk) {
            i_ = sIDXp[cur][t];
            float corr = pwalk16(sCP + i_ * MS, svO);
            float hv = fmaxf(stotS - corr + bd.p[l][0], 0.f);
            out[off + t] = hv;
            shvO[i_] = hv;
            float s2 = hv / srsO[i_];
            s2C[t] = s2;
            s2O[i_] = s2;
        } else if (t < 512) {
            s2C[t] = 0.f;
        }
        if (l == 3) break;
        __syncthreads();
        if (t < 64) {
            float p = 0.f;
#pragma unroll
            for (int j = 0; j < 8; ++j) p += s2C[t * 8 + j];
            p = fbfly(p);
            if (t == 0) stotS = p;
        }
        if (t < 16) sSELp[nxt][t] = 0u;
        __syncthreads();
        float z_ = -1.f;
        if (t < kk) {
            float c2 = pwalk16(sCP + i_ * MS, s2O);
            z_ = fmaxf((stotS - c2) * Wp.p[l + 1][0] + bp.p[l + 1][0], 0.f);
        }
        if (t < 512) szC[t] = (t < kk) ? z_ : -1.f;
        __syncthreads();
        for (int r = wid; r < kk; r += 16) {
            float my = szC[r];
            int cnt = wrank(szC, my, r, lane);
            if (lane == 0 && cnt < knext) {
                int io = sIDXp[cur][r];
                sIDXp[nxt][cnt] = io;
                sHSo[io] = shvO[io] * sigm(my);
                atomicOr(&sSELp[nxt][io >> 5], 1u << (io & 31));
            }
        }
        __syncthreads();
        unsigned Q[16];
        int in2 = 0, pc2 = 0;
        float su2_ = 0.f;
        if (t < knext) {
            in2 = sIDXp[nxt][t];
#pragma unroll
            for (int w = 0; w < 16; ++w) Q[w] = sSELp[nxt][w];
            bool alive = true;
            for (int w2 = 0; w2 < 16 && alive; ++w2) {
                unsigned nb = sSELp[cur][w2] & ~sCP[in2 * MS + w2];
                while (nb) {
                    int b = __ffs((int)nb) - 1;
                    nb &= nb - 1;
                    const unsigned* cj = sCP + (w2 * 32 + b) * MS;
                    unsigned orr = 0;
#pragma unroll
                    for (int w = 0; w < 16; ++w) {
                        Q[w] &= cj[w];
                        orr |= Q[w];
                    }
                    if (!orr) { alive = false; break; }
                }
            }
#pragma unroll
            for (int w = 0; w < 16; ++w) pc2 += __popc(Q[w]);
            float rs = (float)(knext - pc2);
            su2_ = sHSo[in2] * Wd.p[l + 1][t] / rs;
        }
        __syncthreads();
        if (t < knext) {
#pragma unroll
            for (int w = 0; w < 16; ++w) sCP[in2 * MS + w] = Q[w];
            srsO[in2] = (float)(knext - pc2);
            svC[t] = su2_;
            svO[in2] = su2_;
        } else if (t < 512) {
            svC[t] = 0.f;
        }
        __syncthreads();
    }
}

extern "C" void kernel_launch(void* const* d_in, const int* in_sizes, int n_in,
                              void* d_out, int out_size, void* d_ws, size_t ws_size,
                              hipStream_t stream) {
    const float* g = (const float*)d_in[0];
    const float* h = (const float*)d_in[1];
    const float* W_top = (const float*)d_in[2];
    const float* b_top = (const float*)d_in[3];
    P4 Wp, bp, Wd, bd;
    for (int i = 0; i < 4; ++i) {
        Wp.p[i] = (const float*)d_in[4 + 4 * i];
        bp.p[i] = (const float*)d_in[5 + 4 * i];
        Wd.p[i] = (const float*)d_in[6 + 4 * i];
        bd.p[i] = (const float*)d_in[7 + 4 * i];
    }
    float* out = (float*)d_out;

    unsigned* wsu = (unsigned*)d_ws;
    float* V = (float*)(wsu + 0);
    int* IDXA = (int*)(wsu + 512);
    unsigned* SELA = wsu + 1024;
    float* RSUMo = (float*)(wsu + 1056);
    float* SUc = (float*)(wsu + 1568);
    float* SUo = (float*)(wsu + 2080);
    unsigned* CP0 = wsu + 2592;
    unsigned* MA = wsu + 10592;

    k_dot<<<500, 1024, 0, stream>>>(h, W_top, g, V, MA);
    k_mid<<<25, 1024, 0, stream>>>(MA, V, b_top, Wp.p[0], bp.p[0], Wd.p[0], out,
                                   IDXA, SELA, CP0, RSUMo, SUc, SUo);
    k_fin<<<1, 1024, 0, stream>>>(IDXA, SELA, CP0, RSUMo, SUc, SUo, Wp, bp, Wd,
                                  bd, out);
}

// Round 12
// 90.393 us; speedup vs baseline: 1.0377x; 1.0377x over previous
//
#include <hip/hip_runtime.h>

// 2 kernels:
//  k_dot (500 blk): V = h @ W_top (HBM floor), MA = bitmask(g), reset BAR/SEL/FLAG
//  k_all (8 blk x 1024, 8 device barriers ~1us each at 8-block contention):
//    SH -> Z -> rank0 -> hop0 -> m0 -> z1 -> rank1 -> hop1 -> scalar cascade.
//    Complement representation (pooled 2-hop graphs ~99.5% dense): CP rows have
//    ~2-3 bits; matvec = total - complement walk; next hop = intersect of
//    complements with early exit. Fast path when layer-1 graph complete
//    (flag==0); R10-verified general fallback in block 0 otherwise.
// ws (u32): V@0, SHg@512, Zg@1024, IDXg@1536, SELg@2048(16), SEL2g@2064(16),
// FLAG@2080, BAR@2112(32), H1o@2144, RSUMo@2656, SUog@3168, S2og@3680,
// Z1cg@4192, IDX2g@4704, HS2og@5216, SU2cg@5728, CP0g@6240(8000), MAg@14240(8000)

#define MS 16
#define NB 8
struct P4 { const float* p[4]; };

__device__ __forceinline__ float bitselF(unsigned m, int k, float v) {
    int s = ((int)(m << (31 - k))) >> 31;
    return __int_as_float(s & __float_as_int(v));
}
__device__ __forceinline__ float fbfly(float v) {
#pragma unroll
    for (int o = 32; o; o >>= 1) v += __shfl_xor(v, o);
    return v;
}
__device__ __forceinline__ int ibfly(int v) {
#pragma unroll
    for (int o = 32; o; o >>= 1) v += __shfl_xor(v, o);
    return v;
}
__device__ __forceinline__ float sigm(float x) { return 1.f / (1.f + expf(-x)); }

__device__ __forceinline__ void gbar(unsigned* c) {
    __syncthreads();
    if (threadIdx.x == 0) {
        __threadfence();
        __hip_atomic_fetch_add(c, 1u, __ATOMIC_ACQ_REL, __HIP_MEMORY_SCOPE_AGENT);
        while (__hip_atomic_load(c, __ATOMIC_ACQUIRE, __HIP_MEMORY_SCOPE_AGENT) <
               (unsigned)NB)
            __builtin_amdgcn_s_sleep(1);
        __threadfence();
    }
    __syncthreads();
}

// sparse bit-walk over a 16-word LDS row (per-thread; rows have ~2-3 bits)
__device__ __forceinline__ float pwalk16(const unsigned* __restrict__ row,
                                         const float* __restrict__ val) {
    float a = 0.f;
#pragma unroll
    for (int w = 0; w < 16; ++w) {
        unsigned m = row[w];
        while (m) {
            int b = __ffs((int)m) - 1;
            m &= m - 1;
            a += val[(w << 5) + b];
        }
    }
    return a;
}

// wave-cooperative stable rank over padded-512 LDS array (pads = -1)
__device__ __forceinline__ int wrank(const float* __restrict__ sc, float my,
                                     int r, int lane) {
    int cnt = 0;
#pragma unroll
    for (int q = 0; q < 8; ++q) {
        int j = lane + 64 * q;
        float s = sc[j];
        cnt += (s > my) || (s == my && j < r);
    }
    return ibfly(cnt);
}

// K1: V[row] = dot(h[row,:], W_top); MA[row] = bitmask(g row); resets.
__global__ __launch_bounds__(1024) void k_dot(const float* __restrict__ h,
        const float* __restrict__ Wt, const float* __restrict__ g,
        float* __restrict__ V, unsigned* __restrict__ MA,
        unsigned* __restrict__ BAR, unsigned* __restrict__ SELg,
        unsigned* __restrict__ SEL2g, int* __restrict__ FLAGg) {
    int row = blockIdx.x, t = threadIdx.x;
    if (row == 0) {
        if (t < 32) BAR[t] = 0u;
        else if (t < 48) SELg[t - 32] = 0u;
        else if (t < 64) SEL2g[t - 48] = 0u;
        else if (t == 64) FLAGg[0] = 0;
    }
    const float4* h4 = (const float4*)(h + (size_t)row * 32768);
    const float4* w4 = (const float4*)Wt;
    float acc = 0.f;
#pragma unroll
    for (int j = 0; j < 8; ++j) {
        float4 a = h4[t + 1024 * j], b = w4[t + 1024 * j];
        acc = fmaf(a.x, b.x, fmaf(a.y, b.y, fmaf(a.z, b.z, fmaf(a.w, b.w, acc))));
    }
    acc = fbfly(acc);
    __shared__ float red[16];
    if ((t & 63) == 0) red[t >> 6] = acc;
    __syncthreads();
    if (t == 0) {
        float s = 0.f;
        for (int i = 0; i < 16; ++i) s += red[i];
        V[row] = s;
    }
    if (t < 512) {
        float gv = (t < 500) ? g[row * 500 + t] : 0.f;
        unsigned long long bal = __ballot(gv != 0.f);
        if ((t & 63) == 0) {
            int w = t >> 6;
            MA[row * MS + 2 * w] = (unsigned)bal;
            MA[row * MS + 2 * w + 1] = (unsigned)(bal >> 32);
        }
    }
}

// K2: everything else. 8 blocks x 1024 (128 waves), 8 device barriers.
__global__ __launch_bounds__(1024) void k_all(const float* __restrict__ V,
        const unsigned* __restrict__ MAg, unsigned* __restrict__ CP0g,
        float* __restrict__ SHg, float* __restrict__ Zg, int* __restrict__ IDXg,
        unsigned* __restrict__ SELg, float* __restrict__ H1o,
        float* __restrict__ RSUMo, float* __restrict__ SUog,
        float* __restrict__ S2og, float* __restrict__ Z1cg,
        int* __restrict__ IDX2g, unsigned* __restrict__ SEL2g,
        float* __restrict__ HS2og, float* __restrict__ SU2cg,
        int* __restrict__ FLAGg, unsigned* __restrict__ BAR,
        const float* __restrict__ b_top, P4 Wp, P4 bp, P4 Wd, P4 bd,
        float* __restrict__ out) {
    __shared__ __align__(16) unsigned sMA[8000];
    __shared__ __align__(16) unsigned sCP[8000];
    __shared__ float sva[512], sh[512], sz[512];
    __shared__ unsigned sSEL[16], sSEL2[16];
    // fallback-only arrays (LDS total ~91KB, 1 block/CU — we use 8 CUs)
    __shared__ float svC[512], s2C[512], szC[512], svO[512], s2O[512];
    __shared__ float shvO[512], sHSo[512], srsO[512];
    __shared__ int sIDXp[2][512];
    __shared__ unsigned sSELp[2][16];
    __shared__ float stotS;
    int t = threadIdx.x, bid = blockIdx.x, wid = t >> 6, lane = t & 63;
    int gw = bid * 16 + wid;

    // ---- stage A: SH = relu(g . V + b_top); out[0:500] ----
    for (int q = t; q < 2000; q += 1024)
        ((uint4*)sMA)[q] = ((const uint4*)MAg)[q];
    if (t < 512) sva[t] = (t < 500) ? V[t] : 0.f;
    __syncthreads();
    for (int r = gw; r < 500; r += 128) {
        float acc = 0.f;
#pragma unroll
        for (int j = 0; j < 8; ++j) {
            unsigned m = sMA[r * MS + 2 * j + (lane >> 5)];
            acc += bitselF(m, lane & 31, sva[64 * j + lane]);
        }
        acc = fbfly(acc);
        if (lane == 0) {
            float hv = fmaxf(acc + b_top[0], 0.f);
            SHg[r] = hv;
            out[r] = hv;
        }
    }
    gbar(BAR + 0);

    // ---- stage B: Z = relu((g . SH)*Wp0 + bp0) ----
    if (t < 512) sh[t] = (t < 500) ? SHg[t] : 0.f;
    __syncthreads();
    for (int r = gw; r < 500; r += 128) {
        float acc = 0.f;
#pragma unroll
        for (int j = 0; j < 8; ++j) {
            unsigned m = sMA[r * MS + 2 * j + (lane >> 5)];
            acc += bitselF(m, lane & 31, sh[64 * j + lane]);
        }
        acc = fbfly(acc);
        if (lane == 0) Zg[r] = fmaxf(acc * Wp.p[0][0] + bp.p[0][0], 0.f);
    }
    gbar(BAR + 1);

    // ---- stage C: stable top-400 rank ----
    if (t < 512) sz[t] = (t < 500) ? Zg[t] : -1.f;
    __syncthreads();
    for (int r = gw; r < 500; r += 128) {
        float my = sz[r];
        int cnt = wrank(sz, my, r, lane);
        if (lane == 0 && cnt < 400) {
            IDXg[cnt] = r;
            atomicOr(&SELg[r >> 5], 1u << (r & 31));
        }
    }
    gbar(BAR + 2);

    // ---- stage D: hop0 (dense column scan) -> CP0, RSUM, SUo ----
    if (t < 16) sSEL[t] = SELg[t];
    __syncthreads();
    for (int c = gw; c < 400; c += 128) {
        int i = IDXg[c];
        int part = lane >> 4, w = lane & 15;
        unsigned acc = 0;
        for (int k = part; k < 500; k += 4) {
            unsigned sel = (sMA[i * MS + (k >> 5)] >> (k & 31)) & 1u;
            acc |= sMA[k * MS + w] & (0u - sel);
        }
        acc |= (unsigned)__shfl_xor((int)acc, 16);
        acc |= (unsigned)__shfl_xor((int)acc, 32);
        unsigned P = sSEL[w] & ~acc;
        int pc = (lane < 16) ? __popc(P) : 0;
        pc = ibfly(pc);
        if (lane < 16) CP0g[i * MS + lane] = P;
        if (lane == 0) {
            float rs = (float)(400 - pc);
            RSUMo[i] = rs;
            SUog[i] = sh[i] * sigm(sz[i]) * Wd.p[0][c] / rs;
        }
    }
    gbar(BAR + 3);

    // ---- stage E: m0 = relu(tot(SU) - complement + bd0) -> out[500:900] ----
    for (int q = t; q < 2000; q += 1024)
        ((uint4*)sCP)[q] = ((const uint4*)CP0g)[q];
    if (t < 512)
        sva[t] = (t < 500 && ((sSEL[t >> 5] >> (t & 31)) & 1u)) ? SUog[t] : 0.f;
    __syncthreads();
    {
        float a = 0.f;
#pragma unroll
        for (int q = 0; q < 8; ++q) a += sva[lane + 64 * q];
        float tot0 = fbfly(a);
        if (t < 50) {
            int c = t * 8 + bid;
            int i = IDXg[c];
            float corr = pwalk16(sCP + i * MS, sva);
            float h1 = fmaxf(tot0 - corr + bd.p[0][0], 0.f);
            out[500 + c] = h1;
            H1o[i] = h1;
            S2og[i] = h1 / RSUMo[i];
        }
    }
    gbar(BAR + 4);

    // ---- stage F: z1 scores ----
    if (t < 512)
        sva[t] = (t < 500 && ((sSEL[t >> 5] >> (t & 31)) & 1u)) ? S2og[t] : 0.f;
    __syncthreads();
    {
        float a = 0.f;
#pragma unroll
        for (int q = 0; q < 8; ++q) a += sva[lane + 64 * q];
        float tot1 = fbfly(a);
        if (t < 50) {
            int c = t * 8 + bid;
            int i = IDXg[c];
            float c2 = pwalk16(sCP + i * MS, sva);
            Z1cg[c] = fmaxf((tot1 - c2) * Wp.p[1][0] + bp.p[1][0], 0.f);
        }
    }
    gbar(BAR + 5);

    // ---- stage G: rank top-300 of 400 (compact tie-break) ----
    if (t < 512) sz[t] = (t < 400) ? Z1cg[t] : -1.f;
    __syncthreads();
    for (int r = gw; r < 400; r += 128) {
        float my = sz[r];
        int cnt = wrank(sz, my, r, lane);
        if (lane == 0 && cnt < 300) {
            int i = IDXg[r];
            IDX2g[cnt] = i;
            HS2og[i] = H1o[i] * sigm(my);
            atomicOr(&SEL2g[i >> 5], 1u << (i & 31));
        }
    }
    gbar(BAR + 6);

    // ---- stage H: hop1 (intersect complements, early exit) ----
    if (t < 16) sSEL2[t] = SEL2g[t];
    __syncthreads();
    if (t < 38) {
        int c2 = t * 8 + bid;
        if (c2 < 300) {
            int i = IDX2g[c2];
            unsigned P[16];
#pragma unroll
            for (int w = 0; w < 16; ++w) P[w] = sSEL2[w];
            bool alive = true;
            for (int w2 = 0; w2 < 16 && alive; ++w2) {
                unsigned nb = sSEL[w2] & ~sCP[i * MS + w2];
                while (nb) {
                    int b = __ffs((int)nb) - 1;
                    nb &= nb - 1;
                    const unsigned* cj = sCP + (w2 * 32 + b) * MS;
                    unsigned orr = 0;
#pragma unroll
                    for (int w = 0; w < 16; ++w) {
                        P[w] &= cj[w];
                        orr |= P[w];
                    }
                    if (!orr) { alive = false; break; }
                }
            }
            int pc = 0;
#pragma unroll
            for (int w = 0; w < 16; ++w) pc += __popc(P[w]);
            if (pc > 0) atomicOr(FLAGg, 1);
            float rs = (float)(300 - pc);
            SU2cg[c2] = HS2og[i] * Wd.p[1][c2] / rs;
            // state for (rare) general fallback
#pragma unroll
            for (int w = 0; w < 16; ++w) CP0g[i * MS + w] = P[w];
            RSUMo[i] = rs;
        }
    }
    gbar(BAR + 7);

    // ---- stage I: cascade ----
    if (FLAGg[0] == 0) {
        // layers 1-3 graphs complete -> scalar cascade (per-wave redundant)
        float a = 0.f;
#pragma unroll
        for (int q = 0; q < 5; ++q) {
            int j = lane + 64 * q;
            if (j < 300) a += SU2cg[j];
        }
        float tot2 = fbfly(a);
        float h2 = fmaxf(tot2 + bd.p[1][0], 0.f);
        float z2 = fmaxf(h2 * Wp.p[2][0] + bp.p[2][0], 0.f);
        float HS2 = h2 * sigm(z2);
        float b3 = 0.f;
#pragma unroll
        for (int q = 0; q < 4; ++q) {
            int j = lane + 64 * q;
            if (j < 200) b3 += Wd.p[2][j];
        }
        float sw2 = fbfly(b3);
        float h3 = fmaxf(HS2 / 200.f * sw2 + bd.p[2][0], 0.f);
        float z3 = fmaxf(h3 * Wp.p[3][0] + bp.p[3][0], 0.f);
        float HS3 = h3 * sigm(z3);
        float b4 = 0.f;
#pragma unroll
        for (int q = 0; q < 2; ++q) {
            int j = lane + 64 * q;
            if (j < 100) b4 += Wd.p[3][j];
        }
        float sw3 = fbfly(b4);
        float h4 = fmaxf(HS3 / 100.f * sw3 + bd.p[3][0], 0.f);
        int gt = bid * 1024 + t;
        if (gt < 300) out[900 + gt] = h2;
        else if (gt < 500) out[1200 + (gt - 300)] = h3;
        else if (gt < 600) out[1400 + (gt - 500)] = h4;
        return;
    }
    // ---- general fallback (block 0 only; R10-verified structure) ----
    if (bid != 0) return;
    for (int q = t; q < 2000; q += 1024)
        ((uint4*)sCP)[q] = ((const uint4*)CP0g)[q];
    if (t < 512) {
        sIDXp[1][t] = (t < 300) ? IDX2g[t] : 0;
        sIDXp[0][t] = 0;
        svC[t] = (t < 300) ? SU2cg[t] : 0.f;
        srsO[t] = RSUMo[t];
        svO[t] = 0.f;
        s2O[t] = 0.f;
    }
    if (t < 16) {
        sSELp[1][t] = SEL2g[t];
        sSELp[0][t] = 0u;
    }
    __syncthreads();
    if (t < 300) svO[sIDXp[1][t]] = svC[t];
    __syncthreads();
    const int kks[3] = {300, 200, 100};
    const int kns[3] = {200, 100, 0};
    const int offs[3] = {900, 1200, 1400};
    for (int l = 1; l <= 3; ++l) {
        const int kk = kks[l - 1], knext = kns[l - 1], off = offs[l - 1];
        const int cur = l & 1, nxt = cur ^ 1;
        if (t < 64) {
            float p = 0.f;
#pragma unroll
            for (int j = 0; j < 8; ++j) p += svC[t * 8 + j];
            p = fbfly(p);
            if (t == 0) stotS = p;
        }
        __syncthreads();
        int i_ = 0;
        if (t < kk) {
            i_ = sIDXp[cur][t];
            float corr = pwalk16(sCP + i_ * MS, svO);
            float hv = fmaxf(stotS - corr + bd.p[l][0], 0.f);
            out[off + t] = hv;
            shvO[i_] = hv;
            float s2 = hv / srsO[i_];
            s2C[t] = s2;
            s2O[i_] = s2;
        } else if (t < 512) {
            s2C[t] = 0.f;
        }
        if (l == 3) break;
        __syncthreads();
        if (t < 64) {
            float p = 0.f;
#pragma unroll
            for (int j = 0; j < 8; ++j) p += s2C[t * 8 + j];
            p = fbfly(p);
            if (t == 0) stotS = p;
        }
        if (t < 16) sSELp[nxt][t] = 0u;
        __syncthreads();
        float z_ = -1.f;
        if (t < kk) {
            float c2 = pwalk16(sCP + i_ * MS, s2O);
            z_ = fmaxf((stotS - c2) * Wp.p[l + 1][0] + bp.p[l + 1][0], 0.f);
        }
        if (t < 512) szC[t] = (t < kk) ? z_ : -1.f;
        __syncthreads();
        for (int r = wid; r < kk; r += 16) {
            float my = szC[r];
            int cnt = wrank(szC, my, r, lane);
            if (lane == 0 && cnt < knext) {
                int io = sIDXp[cur][r];
                sIDXp[nxt][cnt] = io;
                sHSo[io] = shvO[io] * sigm(my);
                atomicOr(&sSELp[nxt][io >> 5], 1u << (io & 31));
            }
        }
        __syncthreads();
        unsigned Q[16];
        int in2 = 0, pc2 = 0;
        float su2_ = 0.f;
        if (t < knext) {
            in2 = sIDXp[nxt][t];
#pragma unroll
            for (int w = 0; w < 16; ++w) Q[w] = sSELp[nxt][w];
            bool alive = true;
            for (int w2 = 0; w2 < 16 && alive; ++w2) {
                unsigned nb = sSELp[cur][w2] & ~sCP[in2 * MS + w2];
                while (nb) {
                    int b = __ffs((int)nb) - 1;
                    nb &= nb - 1;
                    const unsigned* cj = sCP + (w2 * 32 + b) * MS;
                    unsigned orr = 0;
#pragma unroll
                    for (int w = 0; w < 16; ++w) {
                        Q[w] &= cj[w];
                        orr |= Q[w];
                    }
                    if (!orr) { alive = false; break; }
                }
            }
#pragma unroll
            for (int w = 0; w < 16; ++w) pc2 += __popc(Q[w]);
            float rs = (float)(knext - pc2);
            su2_ = sHSo[in2] * Wd.p[l + 1][t] / rs;
        }
        __syncthreads();
        if (t < knext) {
#pragma unroll
            for (int w = 0; w < 16; ++w) sCP[in2 * MS + w] = Q[w];
            srsO[in2] = (float)(knext - pc2);
            svC[t] = su2_;
            svO[in2] = su2_;
        } else if (t < 512) {
            svC[t] = 0.f;
        }
        __syncthreads();
    }
}

extern "C" void kernel_launch(void* const* d_in, const int* in_sizes, int n_in,
                              void* d_out, int out_size, void* d_ws, size_t ws_size,
                              hipStream_t stream) {
    const float* g = (const float*)d_in[0];
    const float* h = (const float*)d_in[1];
    const float* W_top = (const float*)d_in[2];
    const float* b_top = (const float*)d_in[3];
    P4 Wp, bp, Wd, bd;
    for (int i = 0; i < 4; ++i) {
        Wp.p[i] = (const float*)d_in[4 + 4 * i];
        bp.p[i] = (const float*)d_in[5 + 4 * i];
        Wd.p[i] = (const float*)d_in[6 + 4 * i];
        bd.p[i] = (const float*)d_in[7 + 4 * i];
    }
    float* out = (float*)d_out;

    unsigned* wsu = (unsigned*)d_ws;
    float* V = (float*)(wsu + 0);
    float* SHg = (float*)(wsu + 512);
    float* Zg = (float*)(wsu + 1024);
    int* IDXg = (int*)(wsu + 1536);
    unsigned* SELg = wsu + 2048;
    unsigned* SEL2g = wsu + 2064;
    int* FLAGg = (int*)(wsu + 2080);
    unsigned* BAR = wsu + 2112;
    float* H1o = (float*)(wsu + 2144);
    float* RSUMo = (float*)(wsu + 2656);
    float* SUog = (float*)(wsu + 3168);
    float* S2og = (float*)(wsu + 3680);
    float* Z1cg = (float*)(wsu + 4192);
    int* IDX2g = (int*)(wsu + 4704);
    float* HS2og = (float*)(wsu + 5216);
    float* SU2cg = (float*)(wsu + 5728);
    unsigned* CP0g = wsu + 6240;
    unsigned* MAg = wsu + 14240;

    k_dot<<<500, 1024, 0, stream>>>(h, W_top, g, V, MAg, BAR, SELg, SEL2g, FLAGg);
    k_all<<<NB, 1024, 0, stream>>>(V, MAg, CP0g, SHg, Zg, IDXg, SELg, H1o, RSUMo,
                                   SUog, S2og, Z1cg, IDX2g, SEL2g, HS2og, SU2cg,
                                   FLAGg, BAR, b_top, Wp, bp, Wd, bd, out);
}

// Round 13
// 89.474 us; speedup vs baseline: 1.0483x; 1.0103x over previous
//
#include <hip/hip_runtime.h>

// 2 kernels:
//  k_dot (500 blk): V = h @ W_top (HBM floor), MA = bitmask(g), reset BAR/SEL/FLAG
//  k_all (8 blk x 1024): SH -> Z -> rank0 -> hop0 -> m0 -> z1 -> rank1 -> hop1
//        -> cascade, with FENCE-FREE device barriers: all cross-block data uses
//        relaxed agent-scope atomics (LLC-coherent, bypass non-coherent L2);
//        __syncthreads drains vmcnt before the arrive-add, so counter==NB
//        implies all pre-barrier atomic data stores are LLC-visible. No
//        __threadfence (which emits the ~3-4us L2 writeback on gfx950).
// ws (u32): V@0, SHg@512, Zg@1024, IDXg@1536, SELg@2048(16), SEL2g@2064(16),
// FLAG@2080, BAR@2112(32), H1o@2144, RSUMo@2656, SUog@3168, S2og@3680,
// Z1cg@4192, IDX2g@4704, HS2og@5216, SU2cg@5728, CP0g@6240(8000), MAg@14240(8000)

#define MS 16
#define NB 8
struct P4 { const float* p[4]; };

// ---- relaxed agent-scope (LLC-coherent) access helpers ----
__device__ __forceinline__ float ald(const float* p) {
    return __hip_atomic_load(p, __ATOMIC_RELAXED, __HIP_MEMORY_SCOPE_AGENT);
}
__device__ __forceinline__ void ast(float* p, float v) {
    __hip_atomic_store(p, v, __ATOMIC_RELAXED, __HIP_MEMORY_SCOPE_AGENT);
}
__device__ __forceinline__ unsigned aldu(const unsigned* p) {
    return __hip_atomic_load(p, __ATOMIC_RELAXED, __HIP_MEMORY_SCOPE_AGENT);
}
__device__ __forceinline__ void astu(unsigned* p, unsigned v) {
    __hip_atomic_store(p, v, __ATOMIC_RELAXED, __HIP_MEMORY_SCOPE_AGENT);
}
__device__ __forceinline__ int aldi(const int* p) {
    return __hip_atomic_load(p, __ATOMIC_RELAXED, __HIP_MEMORY_SCOPE_AGENT);
}
__device__ __forceinline__ void asti(int* p, int v) {
    __hip_atomic_store(p, v, __ATOMIC_RELAXED, __HIP_MEMORY_SCOPE_AGENT);
}

__device__ __forceinline__ float bitselF(unsigned m, int k, float v) {
    int s = ((int)(m << (31 - k))) >> 31;
    return __int_as_float(s & __float_as_int(v));
}
__device__ __forceinline__ float fbfly(float v) {
#pragma unroll
    for (int o = 32; o; o >>= 1) v += __shfl_xor(v, o);
    return v;
}
__device__ __forceinline__ int ibfly(int v) {
#pragma unroll
    for (int o = 32; o; o >>= 1) v += __shfl_xor(v, o);
    return v;
}
__device__ __forceinline__ float sigm(float x) { return 1.f / (1.f + expf(-x)); }

// Fence-free device barrier: __syncthreads drains vmcnt(0) for all threads'
// prior atomic stores (they complete at the LLC), THEN lane 0 arrives.
__device__ __forceinline__ void gbar(unsigned* c) {
    __syncthreads();
    if (threadIdx.x == 0) {
        __hip_atomic_fetch_add(c, 1u, __ATOMIC_RELAXED, __HIP_MEMORY_SCOPE_AGENT);
        while (__hip_atomic_load(c, __ATOMIC_RELAXED, __HIP_MEMORY_SCOPE_AGENT) <
               (unsigned)NB) {}
    }
    __syncthreads();
}

// sparse bit-walk over a 16-word LDS row (per-thread; rows have ~2-3 bits)
__device__ __forceinline__ float pwalk16(const unsigned* __restrict__ row,
                                         const float* __restrict__ val) {
    float a = 0.f;
#pragma unroll
    for (int w = 0; w < 16; ++w) {
        unsigned m = row[w];
        while (m) {
            int b = __ffs((int)m) - 1;
            m &= m - 1;
            a += val[(w << 5) + b];
        }
    }
    return a;
}

// wave-cooperative stable rank over padded-512 LDS array (pads = -1)
__device__ __forceinline__ int wrank(const float* __restrict__ sc, float my,
                                     int r, int lane) {
    int cnt = 0;
#pragma unroll
    for (int q = 0; q < 8; ++q) {
        int j = lane + 64 * q;
        float s = sc[j];
        cnt += (s > my) || (s == my && j < r);
    }
    return ibfly(cnt);
}

// K1: V[row] = dot(h[row,:], W_top); MA[row] = bitmask(g row); resets.
__global__ __launch_bounds__(1024) void k_dot(const float* __restrict__ h,
        const float* __restrict__ Wt, const float* __restrict__ g,
        float* __restrict__ V, unsigned* __restrict__ MA,
        unsigned* __restrict__ BAR, unsigned* __restrict__ SELg,
        unsigned* __restrict__ SEL2g, int* __restrict__ FLAGg) {
    int row = blockIdx.x, t = threadIdx.x;
    if (row == 0) {
        if (t < 32) astu(&BAR[t], 0u);
        else if (t < 48) astu(&SELg[t - 32], 0u);
        else if (t < 64) astu(&SEL2g[t - 48], 0u);
        else if (t == 64) asti(FLAGg, 0);
    }
    const float4* h4 = (const float4*)(h + (size_t)row * 32768);
    const float4* w4 = (const float4*)Wt;
    float acc = 0.f;
#pragma unroll
    for (int j = 0; j < 8; ++j) {
        float4 a = h4[t + 1024 * j], b = w4[t + 1024 * j];
        acc = fmaf(a.x, b.x, fmaf(a.y, b.y, fmaf(a.z, b.z, fmaf(a.w, b.w, acc))));
    }
    acc = fbfly(acc);
    __shared__ float red[16];
    if ((t & 63) == 0) red[t >> 6] = acc;
    __syncthreads();
    if (t == 0) {
        float s = 0.f;
        for (int i = 0; i < 16; ++i) s += red[i];
        V[row] = s;
    }
    if (t < 512) {
        float gv = (t < 500) ? g[row * 500 + t] : 0.f;
        unsigned long long bal = __ballot(gv != 0.f);
        if ((t & 63) == 0) {
            int w = t >> 6;
            MA[row * MS + 2 * w] = (unsigned)bal;
            MA[row * MS + 2 * w + 1] = (unsigned)(bal >> 32);
        }
    }
}

// K2: everything else. 8 blocks x 1024 (128 waves), 8 fence-free barriers.
__global__ __launch_bounds__(1024) void k_all(const float* __restrict__ V,
        const unsigned* __restrict__ MAg, unsigned* __restrict__ CP0g,
        float* __restrict__ SHg, float* __restrict__ Zg, int* __restrict__ IDXg,
        unsigned* __restrict__ SELg, float* __restrict__ H1o,
        float* __restrict__ RSUMo, float* __restrict__ SUog,
        float* __restrict__ S2og, float* __restrict__ Z1cg,
        int* __restrict__ IDX2g, unsigned* __restrict__ SEL2g,
        float* __restrict__ HS2og, float* __restrict__ SU2cg,
        int* __restrict__ FLAGg, unsigned* __restrict__ BAR,
        const float* __restrict__ b_top, P4 Wp, P4 bp, P4 Wd, P4 bd,
        float* __restrict__ out) {
    __shared__ __align__(16) unsigned sMA[8000];
    __shared__ unsigned sCP[8000];
    __shared__ float sva[512], sh[512], sz[512];
    __shared__ unsigned sSEL[16], sSEL2[16];
    // fallback-only arrays
    __shared__ float svC[512], s2C[512], szC[512], svO[512], s2O[512];
    __shared__ float shvO[512], sHSo[512], srsO[512];
    __shared__ int sIDXp[2][512];
    __shared__ unsigned sSELp[2][16];
    __shared__ float stotS;
    int t = threadIdx.x, bid = blockIdx.x, wid = t >> 6, lane = t & 63;
    int gw = bid * 16 + wid;

    // ---- stage A: SH = relu(g . V + b_top); out[0:500] ----
    for (int q = t; q < 2000; q += 1024)
        ((uint4*)sMA)[q] = ((const uint4*)MAg)[q];
    if (t < 512) sva[t] = (t < 500) ? V[t] : 0.f;
    __syncthreads();
    for (int r = gw; r < 500; r += 128) {
        float acc = 0.f;
#pragma unroll
        for (int j = 0; j < 8; ++j) {
            unsigned m = sMA[r * MS + 2 * j + (lane >> 5)];
            acc += bitselF(m, lane & 31, sva[64 * j + lane]);
        }
        acc = fbfly(acc);
        if (lane == 0) {
            float hv = fmaxf(acc + b_top[0], 0.f);
            ast(&SHg[r], hv);
            out[r] = hv;
        }
    }
    gbar(BAR + 0);

    // ---- stage B: Z = relu((g . SH)*Wp0 + bp0) ----
    if (t < 512) sh[t] = (t < 500) ? ald(&SHg[t]) : 0.f;
    __syncthreads();
    for (int r = gw; r < 500; r += 128) {
        float acc = 0.f;
#pragma unroll
        for (int j = 0; j < 8; ++j) {
            unsigned m = sMA[r * MS + 2 * j + (lane >> 5)];
            acc += bitselF(m, lane & 31, sh[64 * j + lane]);
        }
        acc = fbfly(acc);
        if (lane == 0) ast(&Zg[r], fmaxf(acc * Wp.p[0][0] + bp.p[0][0], 0.f));
    }
    gbar(BAR + 1);

    // ---- stage C: stable top-400 rank ----
    if (t < 512) sz[t] = (t < 500) ? ald(&Zg[t]) : -1.f;
    __syncthreads();
    for (int r = gw; r < 500; r += 128) {
        float my = sz[r];
        int cnt = wrank(sz, my, r, lane);
        if (lane == 0 && cnt < 400) {
            asti(&IDXg[cnt], r);
            atomicOr(&SELg[r >> 5], 1u << (r & 31));
        }
    }
    gbar(BAR + 2);

    // ---- stage D: hop0 (dense column scan) -> CP0, RSUM, SUo ----
    if (t < 16) sSEL[t] = aldu(&SELg[t]);
    __syncthreads();
    for (int c = gw; c < 400; c += 128) {
        int i = aldi(&IDXg[c]);
        int part = lane >> 4, w = lane & 15;
        unsigned acc = 0;
        for (int k = part; k < 500; k += 4) {
            unsigned sel = (sMA[i * MS + (k >> 5)] >> (k & 31)) & 1u;
            acc |= sMA[k * MS + w] & (0u - sel);
        }
        acc |= (unsigned)__shfl_xor((int)acc, 16);
        acc |= (unsigned)__shfl_xor((int)acc, 32);
        unsigned P = sSEL[w] & ~acc;
        int pc = (lane < 16) ? __popc(P) : 0;
        pc = ibfly(pc);
        if (lane < 16) astu(&CP0g[i * MS + lane], P);
        if (lane == 0) {
            float rs = (float)(400 - pc);
            ast(&RSUMo[i], rs);
            ast(&SUog[i], sh[i] * sigm(sz[i]) * Wd.p[0][c] / rs);
        }
    }
    gbar(BAR + 3);

    // ---- stage E: m0 = relu(tot(SU) - complement + bd0) -> out[500:900] ----
    for (int q = t; q < 8000; q += 1024) sCP[q] = aldu(&CP0g[q]);
    if (t < 512)
        sva[t] = (t < 500 && ((sSEL[t >> 5] >> (t & 31)) & 1u)) ? ald(&SUog[t])
                                                                : 0.f;
    __syncthreads();
    {
        float a = 0.f;
#pragma unroll
        for (int q = 0; q < 8; ++q) a += sva[lane + 64 * q];
        float tot0 = fbfly(a);
        if (t < 50) {
            int c = t * 8 + bid;
            int i = aldi(&IDXg[c]);
            float corr = pwalk16(sCP + i * MS, sva);
            float h1 = fmaxf(tot0 - corr + bd.p[0][0], 0.f);
            out[500 + c] = h1;
            ast(&H1o[i], h1);
            ast(&S2og[i], h1 / ald(&RSUMo[i]));
        }
    }
    gbar(BAR + 4);

    // ---- stage F: z1 scores ----
    if (t < 512)
        sva[t] = (t < 500 && ((sSEL[t >> 5] >> (t & 31)) & 1u)) ? ald(&S2og[t])
                                                                : 0.f;
    __syncthreads();
    {
        float a = 0.f;
#pragma unroll
        for (int q = 0; q < 8; ++q) a += sva[lane + 64 * q];
        float tot1 = fbfly(a);
        if (t < 50) {
            int c = t * 8 + bid;
            int i = aldi(&IDXg[c]);
            float c2 = pwalk16(sCP + i * MS, sva);
            ast(&Z1cg[c], fmaxf((tot1 - c2) * Wp.p[1][0] + bp.p[1][0], 0.f));
        }
    }
    gbar(BAR + 5);

    // ---- stage G: rank top-300 of 400 (compact tie-break) ----
    if (t < 512) sz[t] = (t < 400) ? ald(&Z1cg[t]) : -1.f;
    __syncthreads();
    for (int r = gw; r < 400; r += 128) {
        float my = sz[r];
        int cnt = wrank(sz, my, r, lane);
        if (lane == 0 && cnt < 300) {
            int i = aldi(&IDXg[r]);
            asti(&IDX2g[cnt], i);
            ast(&HS2og[i], ald(&H1o[i]) * sigm(my));
            atomicOr(&SEL2g[i >> 5], 1u << (i & 31));
        }
    }
    gbar(BAR + 6);

    // ---- stage H: hop1 (intersect complements, early exit) ----
    if (t < 16) sSEL2[t] = aldu(&SEL2g[t]);
    __syncthreads();
    if (t < 38) {
        int c2 = t * 8 + bid;
        if (c2 < 300) {
            int i = aldi(&IDX2g[c2]);
            unsigned P[16];
#pragma unroll
            for (int w = 0; w < 16; ++w) P[w] = sSEL2[w];
            bool alive = true;
            for (int w2 = 0; w2 < 16 && alive; ++w2) {
                unsigned nb = sSEL[w2] & ~sCP[i * MS + w2];
                while (nb) {
                    int b = __ffs((int)nb) - 1;
                    nb &= nb - 1;
                    const unsigned* cj = sCP + (w2 * 32 + b) * MS;
                    unsigned orr = 0;
#pragma unroll
                    for (int w = 0; w < 16; ++w) {
                        P[w] &= cj[w];
                        orr |= P[w];
                    }
                    if (!orr) { alive = false; break; }
                }
            }
            int pc = 0;
#pragma unroll
            for (int w = 0; w < 16; ++w) pc += __popc(P[w]);
            if (pc > 0) atomicOr(FLAGg, 1);
            float rs = (float)(300 - pc);
            ast(&SU2cg[c2], ald(&HS2og[i]) * Wd.p[1][c2] / rs);
#pragma unroll
            for (int w = 0; w < 16; ++w) astu(&CP0g[i * MS + w], P[w]);
            ast(&RSUMo[i], rs);
        }
    }
    gbar(BAR + 7);

    // ---- stage I: cascade ----
    if (aldi(FLAGg) == 0) {
        if (t < 512) sva[t] = (t < 300) ? ald(&SU2cg[t]) : 0.f;
        __syncthreads();
        float a = 0.f;
#pragma unroll
        for (int q = 0; q < 8; ++q) a += sva[lane + 64 * q];
        float tot2 = fbfly(a);
        float h2 = fmaxf(tot2 + bd.p[1][0], 0.f);
        float z2 = fmaxf(h2 * Wp.p[2][0] + bp.p[2][0], 0.f);
        float HS2 = h2 * sigm(z2);
        float b3 = 0.f;
#pragma unroll
        for (int q = 0; q < 4; ++q) {
            int j = lane + 64 * q;
            if (j < 200) b3 += Wd.p[2][j];
        }
        float sw2 = fbfly(b3);
        float h3 = fmaxf(HS2 / 200.f * sw2 + bd.p[2][0], 0.f);
        float z3 = fmaxf(h3 * Wp.p[3][0] + bp.p[3][0], 0.f);
        float HS3 = h3 * sigm(z3);
        float b4 = 0.f;
#pragma unroll
        for (int q = 0; q < 2; ++q) {
            int j = lane + 64 * q;
            if (j < 100) b4 += Wd.p[3][j];
        }
        float sw3 = fbfly(b4);
        float h4 = fmaxf(HS3 / 100.f * sw3 + bd.p[3][0], 0.f);
        int gt = bid * 1024 + t;
        if (gt < 300) out[900 + gt] = h2;
        else if (gt < 500) out[1200 + (gt - 300)] = h3;
        else if (gt < 600) out[1400 + (gt - 500)] = h4;
        return;
    }
    // ---- general fallback (block 0 only; R10-verified structure) ----
    if (bid != 0) return;
    for (int q = t; q < 8000; q += 1024) sCP[q] = aldu(&CP0g[q]);
    if (t < 512) {
        sIDXp[1][t] = (t < 300) ? aldi(&IDX2g[t]) : 0;
        sIDXp[0][t] = 0;
        svC[t] = (t < 300) ? ald(&SU2cg[t]) : 0.f;
        srsO[t] = (t < 500) ? ald(&RSUMo[t]) : 1.f;
        svO[t] = 0.f;
        s2O[t] = 0.f;
    }
    if (t < 16) {
        sSELp[1][t] = aldu(&SEL2g[t]);
        sSELp[0][t] = 0u;
    }
    __syncthreads();
    if (t < 300) svO[sIDXp[1][t]] = svC[t];
    __syncthreads();
    const int kks[3] = {300, 200, 100};
    const int kns[3] = {200, 100, 0};
    const int offs[3] = {900, 1200, 1400};
    for (int l = 1; l <= 3; ++l) {
        const int kk = kks[l - 1], knext = kns[l - 1], off = offs[l - 1];
        const int cur = l & 1, nxt = cur ^ 1;
        if (t < 64) {
            float p = 0.f;
#pragma unroll
            for (int j = 0; j < 8; ++j) p += svC[t * 8 + j];
            p = fbfly(p);
            if (t == 0) stotS = p;
        }
        __syncthreads();
        int i_ = 0;
        if (t < kk) {
            i_ = sIDXp[cur][t];
            float corr = pwalk16(sCP + i_ * MS, svO);
            float hv = fmaxf(stotS - corr + bd.p[l][0], 0.f);
            out[off + t] = hv;
            shvO[i_] = hv;
            float s2 = hv / srsO[i_];
            s2C[t] = s2;
            s2O[i_] = s2;
        } else if (t < 512) {
            s2C[t] = 0.f;
        }
        if (l == 3) break;
        __syncthreads();
        if (t < 64) {
            float p = 0.f;
#pragma unroll
            for (int j = 0; j < 8; ++j) p += s2C[t * 8 + j];
            p = fbfly(p);
            if (t == 0) stotS = p;
        }
        if (t < 16) sSELp[nxt][t] = 0u;
        __syncthreads();
        float z_ = -1.f;
        if (t < kk) {
            float c2 = pwalk16(sCP + i_ * MS, s2O);
            z_ = fmaxf((stotS - c2) * Wp.p[l + 1][0] + bp.p[l + 1][0], 0.f);
        }
        if (t < 512) szC[t] = (t < kk) ? z_ : -1.f;
        __syncthreads();
        for (int r = wid; r < kk; r += 16) {
            float my = szC[r];
            int cnt = wrank(szC, my, r, lane);
            if (lane == 0 && cnt < knext) {
                int io = sIDXp[cur][r];
                sIDXp[nxt][cnt] = io;
                sHSo[io] = shvO[io] * sigm(my);
                atomicOr(&sSELp[nxt][io >> 5], 1u << (io & 31));
            }
        }
        __syncthreads();
        unsigned Q[16];
        int in2 = 0, pc2 = 0;
        float su2_ = 0.f;
        if (t < knext) {
            in2 = sIDXp[nxt][t];
#pragma unroll
            for (int w = 0; w < 16; ++w) Q[w] = sSELp[nxt][w];
            bool alive = true;
            for (int w2 = 0; w2 < 16 && alive; ++w2) {
                unsigned nb = sSELp[cur][w2] & ~sCP[in2 * MS + w2];
                while (nb) {
                    int b = __ffs((int)nb) - 1;
                    nb &= nb - 1;
                    const unsigned* cj = sCP + (w2 * 32 + b) * MS;
                    unsigned orr = 0;
#pragma unroll
                    for (int w = 0; w < 16; ++w) {
                        Q[w] &= cj[w];
                        orr |= Q[w];
                    }
                    if (!orr) { alive = false; break; }
                }
            }
#pragma unroll
            for (int w = 0; w < 16; ++w) pc2 += __popc(Q[w]);
            float rs = (float)(knext - pc2);
            su2_ = sHSo[in2] * Wd.p[l + 1][t] / rs;
        }
        __syncthreads();
        if (t < knext) {
#pragma unroll
            for (int w = 0; w < 16; ++w) sCP[in2 * MS + w] = Q[w];
            srsO[in2] = (float)(knext - pc2);
            svC[t] = su2_;
            svO[in2] = su2_;
        } else if (t < 512) {
            svC[t] = 0.f;
        }
        __syncthreads();
    }
}

extern "C" void kernel_launch(void* const* d_in, const int* in_sizes, int n_in,
                              void* d_out, int out_size, void* d_ws, size_t ws_size,
                              hipStream_t stream) {
    const float* g = (const float*)d_in[0];
    const float* h = (const float*)d_in[1];
    const float* W_top = (const float*)d_in[2];
    const float* b_top = (const float*)d_in[3];
    P4 Wp, bp, Wd, bd;
    for (int i = 0; i < 4; ++i) {
        Wp.p[i] = (const float*)d_in[4 + 4 * i];
        bp.p[i] = (const float*)d_in[5 + 4 * i];
        Wd.p[i] = (const float*)d_in[6 + 4 * i];
        bd.p[i] = (const float*)d_in[7 + 4 * i];
    }
    float* out = (float*)d_out;

    unsigned* wsu = (unsigned*)d_ws;
    float* V = (float*)(wsu + 0);
    float* SHg = (float*)(wsu + 512);
    float* Zg = (float*)(wsu + 1024);
    int* IDXg = (int*)(wsu + 1536);
    unsigned* SELg = wsu + 2048;
    unsigned* SEL2g = wsu + 2064;
    int* FLAGg = (int*)(wsu + 2080);
    unsigned* BAR = wsu + 2112;
    float* H1o = (float*)(wsu + 2144);
    float* RSUMo = (float*)(wsu + 2656);
    float* SUog = (float*)(wsu + 3168);
    float* S2og = (float*)(wsu + 3680);
    float* Z1cg = (float*)(wsu + 4192);
    int* IDX2g = (int*)(wsu + 4704);
    float* HS2og = (float*)(wsu + 5216);
    float* SU2cg = (float*)(wsu + 5728);
    unsigned* CP0g = wsu + 6240;
    unsigned* MAg = wsu + 14240;

    k_dot<<<500, 1024, 0, stream>>>(h, W_top, g, V, MAg, BAR, SELg, SEL2g, FLAGg);
    k_all<<<NB, 1024, 0, stream>>>(V, MAg, CP0g, SHg, Zg, IDXg, SELg, H1o, RSUMo,
                                   SUog, S2og, Z1cg, IDX2g, SEL2g, HS2og, SU2cg,
                                   FLAGg, BAR, b_top, Wp, bp, Wd, bd, out);
}

// Round 14
// 73.421 us; speedup vs baseline: 1.2775x; 1.2186x over previous
//
#include <hip/hip_runtime.h>

// 5 kernels, 4 sync boundaries (each boundary ~6-8us on gfx950):
//  k_dot  (500 blk): V = h @ W_top (HBM floor ~10.5us), MA = bitmask(g)
//  k_row  (125 blk): SH = relu(g.V + b_top) -> out[0:500]
//  k_row  (125 blk): Z  = relu((g.SH)*Wp0 + bp0)   (sigmoid monotone: rank on Z)
//  k_hop0 (25 blk x 1024): redundant-per-block top-400 rank (31 rows/wave,
//         ~2us < boundary cost) + wave-per-row dense layer-0 2-hop ->
//         complement CP0 (pooled 2-hop graphs ~99.5% dense), RSUM, SUc.
//  k_fin  (1 blk x 1024): m0 + z1 (total - complement walks) + rank1 + hop1
//         (intersect complements, early exit) + scalar cascade (complete-graph
//         fast path; verified general fallback). out[500:1500].
// ws (u32): V@0, SHg@512, Zg@1024, IDXA@1536, SELA@2048(32), RSUMo@2080,
// SUc@2592, CP0@3104(8000), MA@11104(8000)

#define MS 16
struct P4 { const float* p[4]; };

__device__ __forceinline__ float bitselF(unsigned m, int k, float v) {
    int s = ((int)(m << (31 - k))) >> 31;
    return __int_as_float(s & __float_as_int(v));
}
__device__ __forceinline__ float fbfly(float v) {
#pragma unroll
    for (int o = 32; o; o >>= 1) v += __shfl_xor(v, o);
    return v;
}
__device__ __forceinline__ int ibfly(int v) {
#pragma unroll
    for (int o = 32; o; o >>= 1) v += __shfl_xor(v, o);
    return v;
}
__device__ __forceinline__ float sigm(float x) { return 1.f / (1.f + expf(-x)); }

// sparse bit-walk over a 16-word LDS row (rows have ~2-3 bits set)
__device__ __forceinline__ float pwalk16(const unsigned* __restrict__ row,
                                         const float* __restrict__ val) {
    float a = 0.f;
#pragma unroll
    for (int w = 0; w < 16; ++w) {
        unsigned m = row[w];
        while (m) {
            int b = __ffs((int)m) - 1;
            m &= m - 1;
            a += val[(w << 5) + b];
        }
    }
    return a;
}

// wave-cooperative stable rank over padded-512 LDS array (pads = -1)
__device__ __forceinline__ int wrank(const float* __restrict__ sc, float my,
                                     int r, int lane) {
    int cnt = 0;
#pragma unroll
    for (int q = 0; q < 8; ++q) {
        int j = lane + 64 * q;
        float s = sc[j];
        cnt += (s > my) || (s == my && j < r);
    }
    return ibfly(cnt);
}

// K1: V[row] = dot(h[row,:], W_top); MA[row] = bitmask(g row).
__global__ __launch_bounds__(1024) void k_dot(const float* __restrict__ h,
        const float* __restrict__ Wt, const float* __restrict__ g,
        float* __restrict__ V, unsigned* __restrict__ MA) {
    int row = blockIdx.x, t = threadIdx.x;
    const float4* h4 = (const float4*)(h + (size_t)row * 32768);
    const float4* w4 = (const float4*)Wt;
    float acc = 0.f;
#pragma unroll
    for (int j = 0; j < 8; ++j) {
        float4 a = h4[t + 1024 * j], b = w4[t + 1024 * j];
        acc = fmaf(a.x, b.x, fmaf(a.y, b.y, fmaf(a.z, b.z, fmaf(a.w, b.w, acc))));
    }
    acc = fbfly(acc);
    __shared__ float red[16];
    if ((t & 63) == 0) red[t >> 6] = acc;
    __syncthreads();
    if (t == 0) {
        float s = 0.f;
        for (int i = 0; i < 16; ++i) s += red[i];
        V[row] = s;
    }
    if (t < 512) {
        float gv = (t < 500) ? g[row * 500 + t] : 0.f;
        unsigned long long bal = __ballot(gv != 0.f);
        if ((t & 63) == 0) {
            int w = t >> 6;
            MA[row * MS + 2 * w] = (unsigned)bal;
            MA[row * MS + 2 * w + 1] = (unsigned)(bal >> 32);
        }
    }
}

// K2/K3: wave-per-row masked matvec on sparse g.
// mode 0: y = relu(acc + c0), also out[r]. mode 1: y = relu(acc*c0 + c1).
__global__ __launch_bounds__(256) void k_row(const unsigned* __restrict__ MA,
        const float* __restrict__ x, const float* __restrict__ c0,
        const float* __restrict__ c1, float* __restrict__ y,
        float* __restrict__ out, int mode) {
    __shared__ float sv[512];
    int t = threadIdx.x;
    sv[t] = (t < 500) ? x[t] : 0.f;
    int t2 = t + 256;
    sv[t2] = (t2 < 500) ? x[t2] : 0.f;
    __syncthreads();
    int wid = t >> 6, lane = t & 63;
    int r = blockIdx.x * 4 + wid;
    float acc = 0.f;
#pragma unroll
    for (int j = 0; j < 8; ++j) {
        unsigned m = MA[r * MS + 2 * j + (lane >> 5)];
        acc += bitselF(m, lane & 31, sv[64 * j + lane]);
    }
    acc = fbfly(acc);
    if (lane == 0) {
        if (mode == 0) {
            float hv = fmaxf(acc + c0[0], 0.f);
            out[r] = hv;
            y[r] = hv;
        } else {
            y[r] = fmaxf(acc * c0[0] + c1[0], 0.f);
        }
    }
}

// K4: redundant-per-block top-400 rank + wave-per-row dense layer-0 two-hop.
// 25 blocks x 1024 (16 waves); block b owns compact rows [16b, 16b+16).
__global__ __launch_bounds__(1024) void k_hop0(const unsigned* __restrict__ MA,
        const float* __restrict__ SHg, const float* __restrict__ Zg,
        const float* __restrict__ Wd0, int* __restrict__ IDXA,
        unsigned* __restrict__ SELA, unsigned* __restrict__ CP0,
        float* __restrict__ RSUMo, float* __restrict__ SUc) {
    __shared__ __align__(16) unsigned sMA[8000];
    __shared__ float sh[512], sz[512];
    __shared__ int sIDX[512];
    __shared__ unsigned sSEL[16];
    int t = threadIdx.x, wid = t >> 6, lane = t & 63;
    for (int q = t; q < 2000; q += 1024)
        ((uint4*)sMA)[q] = ((const uint4*)MA)[q];
    if (t < 512) {
        sh[t] = (t < 500) ? SHg[t] : 0.f;
        sz[t] = (t < 500) ? Zg[t] : -1.f;
    }
    if (t < 16) sSEL[t] = 0u;
    __syncthreads();
    // full top-400 rank, redundant per block (deterministic, identical)
    for (int r = wid; r < 500; r += 16) {
        float my = sz[r];
        int cnt = wrank(sz, my, r, lane);
        if (lane == 0 && cnt < 400) {
            sIDX[cnt] = r;
            atomicOr(&sSEL[r >> 5], 1u << (r & 31));
        }
    }
    __syncthreads();
    if (blockIdx.x == 0) {
        if (t < 400) IDXA[t] = sIDX[t];
        if (t < 16) SELA[t] = sSEL[t];
        if (t >= 400 && t < 512) SUc[t] = 0.f;
    }
    // dense 2-hop on sparse g: wave per compact row
    int c = blockIdx.x * 16 + wid;  // < 400
    int i = sIDX[c];
    int part = lane >> 4, w = lane & 15;
    unsigned acc = 0;
    for (int k = part; k < 500; k += 4) {
        unsigned sel = (sMA[i * MS + (k >> 5)] >> (k & 31)) & 1u;
        acc |= sMA[k * MS + w] & (0u - sel);
    }
    acc |= (unsigned)__shfl_xor((int)acc, 16);
    acc |= (unsigned)__shfl_xor((int)acc, 32);
    unsigned P = sSEL[w] & ~acc;  // complement within selection
    int pc = (lane < 16) ? __popc(P) : 0;
    pc = ibfly(pc);
    if (lane < 16) CP0[i * MS + lane] = P;
    if (lane == 0) {
        float rs = (float)(400 - pc);
        RSUMo[i] = rs;
        SUc[c] = sh[i] * sigm(sz[i]) * Wd0[c] / rs;
    }
}

// K5: m0 + z1 + rank1 + hop1 + layers 2-3. Single block x 1024.
// (R11-verified body.)
__global__ __launch_bounds__(1024) void k_fin(const int* __restrict__ IDXA,
        const unsigned* __restrict__ SELAg, const unsigned* __restrict__ CP0g,
        const float* __restrict__ RSUMg, const float* __restrict__ SUcg,
        P4 Wp, P4 bp, P4 Wd, P4 bd, float* __restrict__ out) {
    __shared__ __align__(16) unsigned sCP[8000];
    __shared__ float szC[512], svC[512], s2C[512];
    __shared__ float svO[512], s2O[512], shvO[512], sHSo[512], srsO[512];
    __shared__ int sIDXp[2][512];
    __shared__ unsigned sSELp[2][16];
    __shared__ float sS[8];
    __shared__ float stot0, stot1, stotS;
    __shared__ int sFlag;
    int t = threadIdx.x, wid = t >> 6, lane = t & 63;
    for (int q = t; q < 2000; q += 1024)
        ((uint4*)sCP)[q] = ((const uint4*)CP0g)[q];
    if (t < 512) {
        sIDXp[0][t] = (t < 400) ? IDXA[t] : 0;
        svC[t] = SUcg[t];  // 400..511 zero-padded by k_hop0
    }
    if (t < 16) {
        sSELp[0][t] = SELAg[t];
        sSELp[1][t] = 0u;
    }
    if (t == 0) sFlag = 0;
    __syncthreads();
    if (t < 400) {
        int i = sIDXp[0][t];
        svO[i] = svC[t];
        srsO[i] = RSUMg[i];
    }
    __syncthreads();
    // tot0
    if (t < 64) {
        float p = 0.f;
#pragma unroll
        for (int j = 0; j < 8; ++j) p += svC[t * 8 + j];
        p = fbfly(p);
        if (t == 0) stot0 = p;
    }
    __syncthreads();
    // m0: h1 = relu(tot0 - complement + bd0) -> out[500:900]
    int i0 = 0;
    if (t < 400) {
        i0 = sIDXp[0][t];
        float corr = pwalk16(sCP + i0 * MS, svO);
        float h1 = fmaxf(stot0 - corr + bd.p[0][0], 0.f);
        out[500 + t] = h1;
        shvO[i0] = h1;
        float s2 = h1 / srsO[i0];
        s2C[t] = s2;
        s2O[i0] = s2;
    } else if (t < 512) {
        s2C[t] = 0.f;
    }
    __syncthreads();
    // tot1
    if (t < 64) {
        float p = 0.f;
#pragma unroll
        for (int j = 0; j < 8; ++j) p += s2C[t * 8 + j];
        p = fbfly(p);
        if (t == 0) stot1 = p;
    }
    __syncthreads();
    // z1
    if (t < 400) {
        float c2 = pwalk16(sCP + i0 * MS, s2O);
        szC[t] = fmaxf((stot1 - c2) * Wp.p[1][0] + bp.p[1][0], 0.f);
    } else if (t < 512) {
        szC[t] = -1.f;
    }
    __syncthreads();
    // rank1: top-300 of 400 (compact tie-break)
    for (int r = wid; r < 400; r += 16) {
        float my = szC[r];
        int cnt = wrank(szC, my, r, lane);
        if (lane == 0 && cnt < 300) {
            int io = sIDXp[0][r];
            sIDXp[1][cnt] = io;
            sHSo[io] = shvO[io] * sigm(my);
            atomicOr(&sSELp[1][io >> 5], 1u << (io & 31));
        }
    }
    __syncthreads();
    // hop1: intersect of complements, early exit; flag if any row nonempty
    unsigned P[16];
    int inew = 0, pc = 0;
    float su_ = 0.f;
    if (t < 300) {
        inew = sIDXp[1][t];
#pragma unroll
        for (int w = 0; w < 16; ++w) P[w] = sSELp[1][w];
        bool alive = true;
        for (int w2 = 0; w2 < 16 && alive; ++w2) {
            unsigned nb = sSELp[0][w2] & ~sCP[inew * MS + w2];
            while (nb) {
                int b = __ffs((int)nb) - 1;
                nb &= nb - 1;
                const unsigned* cj = sCP + (w2 * 32 + b) * MS;
                unsigned orr = 0;
#pragma unroll
                for (int w = 0; w < 16; ++w) {
                    P[w] &= cj[w];
                    orr |= P[w];
                }
                if (!orr) { alive = false; break; }
            }
        }
#pragma unroll
        for (int w = 0; w < 16; ++w) pc += __popc(P[w]);
        if (pc > 0) atomicOr(&sFlag, 1);
        float rs = (float)(300 - pc);
        su_ = sHSo[inew] * Wd.p[1][t] / rs;
    }
    __syncthreads();
    if (t < 300) {
#pragma unroll
        for (int w = 0; w < 16; ++w) sCP[inew * MS + w] = P[w];
        srsO[inew] = (float)(300 - pc);
        svC[t] = su_;
        svO[inew] = su_;
    } else if (t < 512) {
        svC[t] = 0.f;
    }
    __syncthreads();
    if (sFlag == 0) {
        // ---- scalar fast path: layers 1-3 graphs are complete ----
        if (t < 64) {
            float p = 0.f;
#pragma unroll
            for (int j = 0; j < 8; ++j) p += svC[t * 8 + j];
            p = fbfly(p);
            if (t == 0) {
                float h2 = fmaxf(p + bd.p[1][0], 0.f);
                float z2 = fmaxf(h2 * Wp.p[2][0] + bp.p[2][0], 0.f);
                sS[0] = h2;
                sS[1] = h2 * sigm(z2);
            }
        }
        __syncthreads();
        float HS2 = sS[1];
        if (t < 512) s2C[t] = (t < 200) ? HS2 * Wd.p[2][t] / 200.f : 0.f;
        __syncthreads();
        if (t < 64) {
            float p = 0.f;
#pragma unroll
            for (int j = 0; j < 8; ++j) p += s2C[t * 8 + j];
            p = fbfly(p);
            if (t == 0) {
                float h3 = fmaxf(p + bd.p[2][0], 0.f);
                float z3 = fmaxf(h3 * Wp.p[3][0] + bp.p[3][0], 0.f);
                sS[2] = h3;
                sS[3] = h3 * sigm(z3);
            }
        }
        __syncthreads();
        float HS3 = sS[3];
        if (t < 512) s2C[t] = (t < 100) ? HS3 * Wd.p[3][t] / 100.f : 0.f;
        __syncthreads();
        if (t < 64) {
            float p = 0.f;
#pragma unroll
            for (int j = 0; j < 8; ++j) p += s2C[t * 8 + j];
            p = fbfly(p);
            if (t == 0) sS[4] = fmaxf(p + bd.p[3][0], 0.f);
        }
        __syncthreads();
        if (t < 300) out[900 + t] = sS[0];
        else if (t < 500) out[1200 + (t - 300)] = sS[2];
        else if (t < 600) out[1400 + (t - 500)] = sS[4];
        return;
    }
    // ---- general fallback (correct; not expected to execute) ----
    const int kks[3] = {300, 200, 100};
    const int kns[3] = {200, 100, 0};
    const int offs[3] = {900, 1200, 1400};
    for (int l = 1; l <= 3; ++l) {
        const int kk = kks[l - 1], knext = kns[l - 1], off = offs[l - 1];
        const int cur = l & 1, nxt = cur ^ 1;
        if (t < 64) {
            float p = 0.f;
#pragma unroll
            for (int j = 0; j < 8; ++j) p += svC[t * 8 + j];
            p = fbfly(p);
            if (t == 0) stotS = p;
        }
        __syncthreads();
        int i_ = 0;
        if (t < kk) {
            i_ = sIDXp[cur][t];
            float corr = pwalk16(sCP + i_ * MS, svO);
            float hv = fmaxf(stotS - corr + bd.p[l][0], 0.f);
            out[off + t] = hv;
            shvO[i_] = hv;
            float s2 = hv / srsO[i_];
            s2C[t] = s2;
            s2O[i_] = s2;
        } else if (t < 512) {
            s2C[t] = 0.f;
        }
        if (l == 3) break;
        __syncthreads();
        if (t < 64) {
            float p = 0.f;
#pragma unroll
            for (int j = 0; j < 8; ++j) p += s2C[t * 8 + j];
            p = fbfly(p);
            if (t == 0) stotS = p;
        }
        if (t < 16) sSELp[nxt][t] = 0u;
        __syncthreads();
        float z_ = -1.f;
        if (t < kk) {
            float c2 = pwalk16(sCP + i_ * MS, s2O);
            z_ = fmaxf((stotS - c2) * Wp.p[l + 1][0] + bp.p[l + 1][0], 0.f);
        }
        if (t < 512) szC[t] = (t < kk) ? z_ : -1.f;
        __syncthreads();
        for (int r = wid; r < kk; r += 16) {
            float my = szC[r];
            int cnt = wrank(szC, my, r, lane);
            if (lane == 0 && cnt < knext) {
                int io = sIDXp[cur][r];
                sIDXp[nxt][cnt] = io;
                sHSo[io] = shvO[io] * sigm(my);
                atomicOr(&sSELp[nxt][io >> 5], 1u << (io & 31));
            }
        }
        __syncthreads();
        unsigned Q[16];
        int in2 = 0, pc2 = 0;
        float su2_ = 0.f;
        if (t < knext) {
            in2 = sIDXp[nxt][t];
#pragma unroll
            for (int w = 0; w < 16; ++w) Q[w] = sSELp[nxt][w];
            bool alive = true;
            for (int w2 = 0; w2 < 16 && alive; ++w2) {
                unsigned nb = sSELp[cur][w2] & ~sCP[in2 * MS + w2];
                while (nb) {
                    int b = __ffs((int)nb) - 1;
                    nb &= nb - 1;
                    const unsigned* cj = sCP + (w2 * 32 + b) * MS;
                    unsigned orr = 0;
#pragma unroll
                    for (int w = 0; w < 16; ++w) {
                        Q[w] &= cj[w];
                        orr |= Q[w];
                    }
                    if (!orr) { alive = false; break; }
                }
            }
#pragma unroll
            for (int w = 0; w < 16; ++w) pc2 += __popc(Q[w]);
            float rs = (float)(knext - pc2);
            su2_ = sHSo[in2] * Wd.p[l + 1][t] / rs;
        }
        __syncthreads();
        if (t < knext) {
#pragma unroll
            for (int w = 0; w < 16; ++w) sCP[in2 * MS + w] = Q[w];
            srsO[in2] = (float)(knext - pc2);
            svC[t] = su2_;
            svO[in2] = su2_;
        } else if (t < 512) {
            svC[t] = 0.f;
        }
        __syncthreads();
    }
}

extern "C" void kernel_launch(void* const* d_in, const int* in_sizes, int n_in,
                              void* d_out, int out_size, void* d_ws, size_t ws_size,
                              hipStream_t stream) {
    const float* g = (const float*)d_in[0];
    const float* h = (const float*)d_in[1];
    const float* W_top = (const float*)d_in[2];
    const float* b_top = (const float*)d_in[3];
    P4 Wp, bp, Wd, bd;
    for (int i = 0; i < 4; ++i) {
        Wp.p[i] = (const float*)d_in[4 + 4 * i];
        bp.p[i] = (const float*)d_in[5 + 4 * i];
        Wd.p[i] = (const float*)d_in[6 + 4 * i];
        bd.p[i] = (const float*)d_in[7 + 4 * i];
    }
    float* out = (float*)d_out;

    unsigned* wsu = (unsigned*)d_ws;
    float* V = (float*)(wsu + 0);
    float* SHg = (float*)(wsu + 512);
    float* Zg = (float*)(wsu + 1024);
    int* IDXA = (int*)(wsu + 1536);
    unsigned* SELA = wsu + 2048;
    float* RSUMo = (float*)(wsu + 2080);
    float* SUc = (float*)(wsu + 2592);
    unsigned* CP0 = wsu + 3104;
    unsigned* MA = wsu + 11104;

    k_dot<<<500, 1024, 0, stream>>>(h, W_top, g, V, MA);
    k_row<<<125, 256, 0, stream>>>(MA, V, b_top, nullptr, SHg, out, 0);
    k_row<<<125, 256, 0, stream>>>(MA, SHg, Wp.p[0], bp.p[0], Zg, nullptr, 1);
    k_hop0<<<25, 1024, 0, stream>>>(MA, SHg, Zg, Wd.p[0], IDXA, SELA, CP0,
                                    RSUMo, SUc);
    k_fin<<<1, 1024, 0, stream>>>(IDXA, SELA, CP0, RSUMo, SUc, Wp, bp, Wd, bd,
                                  out);
}

// Round 15
// 55.604 us; speedup vs baseline: 1.6869x; 1.3204x over previous
//
#include <hip/hip_runtime.h>

// 5 kernels, 4 boundaries, ZERO redundant work:
//  k_dot (500 blk): V = h @ W_top (HBM floor ~10.5us), MA = bitmask(g)
//  k_row (125 blk): SH = relu(g.V + b_top) -> out[0:500]
//  k_row (125 blk): Z  = relu((g.SH)*Wp0 + bp0)  (sigmoid monotone)
//  k_rh  (125 blk, wave/orig-row): rank_i (1 wrank/wave) -> IDXA[rank]=i,
//        HSo[i]; selected rows also compute un2 (2-hop nbhd in full g) and
//        store CPP[i] = ~un2 & mask500 (~1-3 bits). SEL-projection deferred.
//  k_fin (1 blk x 1024): rebuild SEL from IDXA, CP = CPP & SEL, RSUM, SU,
//        m0 + z1 (total - complement walks) + rank1 (paired/packed wrank)
//        + hop1 (intersect complements, early exit) + scalar cascade
//        (complete-graph fast path; verified general fallback). out[500:1500].
// ws (u32): V@0, SHg@512, Zg@1024, IDXA@1536, HSo@2048, CPP@2560(8000),
// MA@10560(8000)

#define MS 16
struct P4 { const float* p[4]; };

__device__ __forceinline__ float bitselF(unsigned m, int k, float v) {
    int s = ((int)(m << (31 - k))) >> 31;
    return __int_as_float(s & __float_as_int(v));
}
__device__ __forceinline__ float fbfly(float v) {
#pragma unroll
    for (int o = 32; o; o >>= 1) v += __shfl_xor(v, o);
    return v;
}
__device__ __forceinline__ int ibfly(int v) {
#pragma unroll
    for (int o = 32; o; o >>= 1) v += __shfl_xor(v, o);
    return v;
}
__device__ __forceinline__ float sigm(float x) { return 1.f / (1.f + expf(-x)); }

// sparse bit-walk over a 16-word LDS row (rows have ~1-3 bits set)
__device__ __forceinline__ float pwalk16(const unsigned* __restrict__ row,
                                         const float* __restrict__ val) {
    float a = 0.f;
#pragma unroll
    for (int w = 0; w < 16; ++w) {
        unsigned m = row[w];
        while (m) {
            int b = __ffs((int)m) - 1;
            m &= m - 1;
            a += val[(w << 5) + b];
        }
    }
    return a;
}

// wave-cooperative stable rank over padded-512 LDS array (pads = -1)
__device__ __forceinline__ int wrank(const float* __restrict__ sc, float my,
                                     int r, int lane) {
    int cnt = 0;
#pragma unroll
    for (int q = 0; q < 8; ++q) {
        int j = lane + 64 * q;
        float s = sc[j];
        cnt += (s > my) || (s == my && j < r);
    }
    return ibfly(cnt);
}

// K1: V[row] = dot(h[row,:], W_top); MA[row] = bitmask(g row).
__global__ __launch_bounds__(1024) void k_dot(const float* __restrict__ h,
        const float* __restrict__ Wt, const float* __restrict__ g,
        float* __restrict__ V, unsigned* __restrict__ MA) {
    int row = blockIdx.x, t = threadIdx.x;
    const float4* h4 = (const float4*)(h + (size_t)row * 32768);
    const float4* w4 = (const float4*)Wt;
    float acc = 0.f;
#pragma unroll
    for (int j = 0; j < 8; ++j) {
        float4 a = h4[t + 1024 * j], b = w4[t + 1024 * j];
        acc = fmaf(a.x, b.x, fmaf(a.y, b.y, fmaf(a.z, b.z, fmaf(a.w, b.w, acc))));
    }
    acc = fbfly(acc);
    __shared__ float red[16];
    if ((t & 63) == 0) red[t >> 6] = acc;
    __syncthreads();
    if (t == 0) {
        float s = 0.f;
        for (int i = 0; i < 16; ++i) s += red[i];
        V[row] = s;
    }
    if (t < 512) {
        float gv = (t < 500) ? g[row * 500 + t] : 0.f;
        unsigned long long bal = __ballot(gv != 0.f);
        if ((t & 63) == 0) {
            int w = t >> 6;
            MA[row * MS + 2 * w] = (unsigned)bal;
            MA[row * MS + 2 * w + 1] = (unsigned)(bal >> 32);
        }
    }
}

// K2/K3: wave-per-row masked matvec on sparse g.
// mode 0: y = relu(acc + c0), also out[r]. mode 1: y = relu(acc*c0 + c1).
__global__ __launch_bounds__(256) void k_row(const unsigned* __restrict__ MA,
        const float* __restrict__ x, const float* __restrict__ c0,
        const float* __restrict__ c1, float* __restrict__ y,
        float* __restrict__ out, int mode) {
    __shared__ float sv[512];
    int t = threadIdx.x;
    sv[t] = (t < 500) ? x[t] : 0.f;
    int t2 = t + 256;
    sv[t2] = (t2 < 500) ? x[t2] : 0.f;
    __syncthreads();
    int wid = t >> 6, lane = t & 63;
    int r = blockIdx.x * 4 + wid;
    float acc = 0.f;
#pragma unroll
    for (int j = 0; j < 8; ++j) {
        unsigned m = MA[r * MS + 2 * j + (lane >> 5)];
        acc += bitselF(m, lane & 31, sv[64 * j + lane]);
    }
    acc = fbfly(acc);
    if (lane == 0) {
        if (mode == 0) {
            float hv = fmaxf(acc + c0[0], 0.f);
            out[r] = hv;
            y[r] = hv;
        } else {
            y[r] = fmaxf(acc * c0[0] + c1[0], 0.f);
        }
    }
}

// K4: rank + un2, wave per ORIG row (zero redundancy).
// 125 blocks x 256 (4 waves); wave handles orig row i = 4*blockIdx + wid.
__global__ __launch_bounds__(256) void k_rh(const unsigned* __restrict__ MA,
        const float* __restrict__ SHg, const float* __restrict__ Zg,
        int* __restrict__ IDXA, float* __restrict__ HSo,
        unsigned* __restrict__ CPP) {
    __shared__ __align__(16) unsigned sMA[8000];
    __shared__ float sz[512];
    int t = threadIdx.x, wid = t >> 6, lane = t & 63;
    for (int q = t; q < 2000; q += 256)
        ((uint4*)sMA)[q] = ((const uint4*)MA)[q];
    if (t < 500) sz[t] = Zg[t];
    else if (t < 512) sz[t] = -1.f;
    int t2 = t + 256;
    if (t2 < 500) sz[t2] = Zg[t2];
    else if (t2 < 512) sz[t2] = -1.f;
    __syncthreads();
    int i = blockIdx.x * 4 + wid;
    float my = sz[i];
    int rank = wrank(sz, my, i, lane);
    if (rank >= 400) return;  // wave-uniform exit
    if (lane == 0) {
        IDXA[rank] = i;
        HSo[i] = SHg[i] * sigm(my);
    }
    // un2 = OR of g-rows over neighbors of i (dense column scan, 4-part)
    int part = lane >> 4, w = lane & 15;
    unsigned acc = 0;
    for (int k = part; k < 500; k += 4) {
        unsigned sel = (sMA[i * MS + (k >> 5)] >> (k & 31)) & 1u;
        acc |= sMA[k * MS + w] & (0u - sel);
    }
    acc |= (unsigned)__shfl_xor((int)acc, 16);
    acc |= (unsigned)__shfl_xor((int)acc, 32);
    if (lane < 16) {
        unsigned m500 = (lane < 15) ? 0xffffffffu : 0xfffffu;  // 500 bits
        CPP[i * MS + lane] = ~acc & m500;
    }
}

// K5: SEL-build + CP-project + m0 + z1 + rank1 + hop1 + cascade. 1 blk x 1024.
__global__ __launch_bounds__(1024) void k_fin(const int* __restrict__ IDXA,
        const unsigned* __restrict__ CPP, const float* __restrict__ HSo,
        P4 Wp, P4 bp, P4 Wd, P4 bd, float* __restrict__ out) {
    __shared__ __align__(16) unsigned sCP[8000];
    __shared__ float szC[512], svC[512], s2C[512];
    __shared__ float svO[512], s2O[512], shvO[512], sHSo[512], srsO[512];
    __shared__ int sIDXp[2][512];
    __shared__ unsigned sSELp[2][16];
    __shared__ float sS[8];
    __shared__ float stot0, stot1, stotS;
    __shared__ int sFlag;
    int t = threadIdx.x, wid = t >> 6, lane = t & 63;
    if (t < 512) sIDXp[0][t] = (t < 400) ? IDXA[t] : 0;
    if (t < 16) {
        sSELp[0][t] = 0u;
        sSELp[1][t] = 0u;
    }
    if (t == 0) sFlag = 0;
    __syncthreads();
    if (t < 400) {
        int i = sIDXp[0][t];
        atomicOr(&sSELp[0][i >> 5], 1u << (i & 31));
    }
    __syncthreads();
    // CP projection: sCP[i] = CPP[i] & SEL (selected rows only)
    for (int q = t; q < 6400; q += 1024) {
        int c = q >> 4, w = q & 15;
        int i = sIDXp[0][c];
        sCP[i * MS + w] = CPP[i * MS + w] & sSELp[0][w];
    }
    __syncthreads();
    // RSUM + SU (compact + orig)
    if (t < 400) {
        int i = sIDXp[0][t];
        int pc = 0;
#pragma unroll
        for (int w = 0; w < 16; ++w) pc += __popc(sCP[i * MS + w]);
        float rs = (float)(400 - pc);
        srsO[i] = rs;
        float su = HSo[i] * Wd.p[0][t] / rs;
        svC[t] = su;
        svO[i] = su;
    } else if (t < 512) {
        svC[t] = 0.f;
    }
    __syncthreads();
    // tot0
    if (t < 64) {
        float p = 0.f;
#pragma unroll
        for (int j = 0; j < 8; ++j) p += svC[t * 8 + j];
        p = fbfly(p);
        if (t == 0) stot0 = p;
    }
    __syncthreads();
    // m0: h1 = relu(tot0 - complement + bd0) -> out[500:900]
    int i0 = 0;
    if (t < 400) {
        i0 = sIDXp[0][t];
        float corr = pwalk16(sCP + i0 * MS, svO);
        float h1 = fmaxf(stot0 - corr + bd.p[0][0], 0.f);
        out[500 + t] = h1;
        shvO[i0] = h1;
        float s2 = h1 / srsO[i0];
        s2C[t] = s2;
        s2O[i0] = s2;
    } else if (t < 512) {
        s2C[t] = 0.f;
    }
    __syncthreads();
    // tot1
    if (t < 64) {
        float p = 0.f;
#pragma unroll
        for (int j = 0; j < 8; ++j) p += s2C[t * 8 + j];
        p = fbfly(p);
        if (t == 0) stot1 = p;
    }
    __syncthreads();
    // z1
    if (t < 400) {
        float c2 = pwalk16(sCP + i0 * MS, s2O);
        szC[t] = fmaxf((stot1 - c2) * Wp.p[1][0] + bp.p[1][0], 0.f);
    } else if (t < 512) {
        szC[t] = -1.f;
    }
    __syncthreads();
    // rank1: top-300 of 400, paired rows with PACKED counts (one bfly / 2 rows)
    for (int r0 = wid * 2; r0 < 400; r0 += 32) {
        int r1 = r0 + 1;  // always < 400 (r0 even, max 398)
        float my0 = szC[r0], my1 = szC[r1];
        int cnt = 0;
#pragma unroll
        for (int q = 0; q < 8; ++q) {
            int j = lane + 64 * q;
            float s = szC[j];
            cnt += (s > my0) || (s == my0 && j < r0);
            cnt += ((s > my1) || (s == my1 && j < r1)) << 16;
        }
        cnt = ibfly(cnt);
        if (lane == 0) {
            int c0 = cnt & 0xffff, c1 = cnt >> 16;
            if (c0 < 300) {
                int io = sIDXp[0][r0];
                sIDXp[1][c0] = io;
                sHSo[io] = shvO[io] * sigm(my0);
                atomicOr(&sSELp[1][io >> 5], 1u << (io & 31));
            }
            if (c1 < 300) {
                int io = sIDXp[0][r1];
                sIDXp[1][c1] = io;
                sHSo[io] = shvO[io] * sigm(my1);
                atomicOr(&sSELp[1][io >> 5], 1u << (io & 31));
            }
        }
    }
    __syncthreads();
    // hop1: intersect of complements, early exit; flag if any row nonempty
    unsigned P[16];
    int inew = 0, pc = 0;
    float su_ = 0.f;
    if (t < 300) {
        inew = sIDXp[1][t];
#pragma unroll
        for (int w = 0; w < 16; ++w) P[w] = sSELp[1][w];
        bool alive = true;
        for (int w2 = 0; w2 < 16 && alive; ++w2) {
            unsigned nb = sSELp[0][w2] & ~sCP[inew * MS + w2];
            while (nb) {
                int b = __ffs((int)nb) - 1;
                nb &= nb - 1;
                const unsigned* cj = sCP + (w2 * 32 + b) * MS;
                unsigned orr = 0;
#pragma unroll
                for (int w = 0; w < 16; ++w) {
                    P[w] &= cj[w];
                    orr |= P[w];
                }
                if (!orr) { alive = false; break; }
            }
        }
#pragma unroll
        for (int w = 0; w < 16; ++w) pc += __popc(P[w]);
        if (pc > 0) atomicOr(&sFlag, 1);
        float rs = (float)(300 - pc);
        su_ = sHSo[inew] * Wd.p[1][t] / rs;
    }
    __syncthreads();
    if (t < 300) {
#pragma unroll
        for (int w = 0; w < 16; ++w) sCP[inew * MS + w] = P[w];
        srsO[inew] = (float)(300 - pc);
        svC[t] = su_;
        svO[inew] = su_;
    } else if (t < 512) {
        svC[t] = 0.f;
    }
    __syncthreads();
    if (sFlag == 0) {
        // ---- scalar fast path: layers 1-3 graphs are complete ----
        if (t < 64) {
            float p = 0.f;
#pragma unroll
            for (int j = 0; j < 8; ++j) p += svC[t * 8 + j];
            p = fbfly(p);
            if (t == 0) {
                float h2 = fmaxf(p + bd.p[1][0], 0.f);
                float z2 = fmaxf(h2 * Wp.p[2][0] + bp.p[2][0], 0.f);
                sS[0] = h2;
                sS[1] = h2 * sigm(z2);
            }
        }
        __syncthreads();
        float HS2 = sS[1];
        if (t < 512) s2C[t] = (t < 200) ? HS2 * Wd.p[2][t] / 200.f : 0.f;
        __syncthreads();
        if (t < 64) {
            float p = 0.f;
#pragma unroll
            for (int j = 0; j < 8; ++j) p += s2C[t * 8 + j];
            p = fbfly(p);
            if (t == 0) {
                float h3 = fmaxf(p + bd.p[2][0], 0.f);
                float z3 = fmaxf(h3 * Wp.p[3][0] + bp.p[3][0], 0.f);
                sS[2] = h3;
                sS[3] = h3 * sigm(z3);
            }
        }
        __syncthreads();
        float HS3 = sS[3];
        if (t < 512) s2C[t] = (t < 100) ? HS3 * Wd.p[3][t] / 100.f : 0.f;
        __syncthreads();
        if (t < 64) {
            float p = 0.f;
#pragma unroll
            for (int j = 0; j < 8; ++j) p += s2C[t * 8 + j];
            p = fbfly(p);
            if (t == 0) sS[4] = fmaxf(p + bd.p[3][0], 0.f);
        }
        __syncthreads();
        if (t < 300) out[900 + t] = sS[0];
        else if (t < 500) out[1200 + (t - 300)] = sS[2];
        else if (t < 600) out[1400 + (t - 500)] = sS[4];
        return;
    }
    // ---- general fallback (correct; not expected to execute) ----
    const int kks[3] = {300, 200, 100};
    const int kns[3] = {200, 100, 0};
    const int offs[3] = {900, 1200, 1400};
    for (int l = 1; l <= 3; ++l) {
        const int kk = kks[l - 1], knext = kns[l - 1], off = offs[l - 1];
        const int cur = l & 1, nxt = cur ^ 1;
        if (t < 64) {
            float p = 0.f;
#pragma unroll
            for (int j = 0; j < 8; ++j) p += svC[t * 8 + j];
            p = fbfly(p);
            if (t == 0) stotS = p;
        }
        __syncthreads();
        int i_ = 0;
        if (t < kk) {
            i_ = sIDXp[cur][t];
            float corr = pwalk16(sCP + i_ * MS, svO);
            float hv = fmaxf(stotS - corr + bd.p[l][0], 0.f);
            out[off + t] = hv;
            shvO[i_] = hv;
            float s2 = hv / srsO[i_];
            s2C[t] = s2;
            s2O[i_] = s2;
        } else if (t < 512) {
            s2C[t] = 0.f;
        }
        if (l == 3) break;
        __syncthreads();
        if (t < 64) {
            float p = 0.f;
#pragma unroll
            for (int j = 0; j < 8; ++j) p += s2C[t * 8 + j];
            p = fbfly(p);
            if (t == 0) stotS = p;
        }
        if (t < 16) sSELp[nxt][t] = 0u;
        __syncthreads();
        float z_ = -1.f;
        if (t < kk) {
            float c2 = pwalk16(sCP + i_ * MS, s2O);
            z_ = fmaxf((stotS - c2) * Wp.p[l + 1][0] + bp.p[l + 1][0], 0.f);
        }
        if (t < 512) szC[t] = (t < kk) ? z_ : -1.f;
        __syncthreads();
        for (int r = wid; r < kk; r += 16) {
            float my = szC[r];
            int cnt = wrank(szC, my, r, lane);
            if (lane == 0 && cnt < knext) {
                int io = sIDXp[cur][r];
                sIDXp[nxt][cnt] = io;
                sHSo[io] = shvO[io] * sigm(my);
                atomicOr(&sSELp[nxt][io >> 5], 1u << (io & 31));
            }
        }
        __syncthreads();
        unsigned Q[16];
        int in2 = 0, pc2 = 0;
        float su2_ = 0.f;
        if (t < knext) {
            in2 = sIDXp[nxt][t];
#pragma unroll
            for (int w = 0; w < 16; ++w) Q[w] = sSELp[nxt][w];
            bool alive = true;
            for (int w2 = 0; w2 < 16 && alive; ++w2) {
                unsigned nb = sSELp[cur][w2] & ~sCP[in2 * MS + w2];
                while (nb) {
                    int b = __ffs((int)nb) - 1;
                    nb &= nb - 1;
                    const unsigned* cj = sCP + (w2 * 32 + b) * MS;
                    unsigned orr = 0;
#pragma unroll
                    for (int w = 0; w < 16; ++w) {
                        Q[w] &= cj[w];
                        orr |= Q[w];
                    }
                    if (!orr) { alive = false; break; }
                }
            }
#pragma unroll
            for (int w = 0; w < 16; ++w) pc2 += __popc(Q[w]);
            float rs = (float)(knext - pc2);
            su2_ = sHSo[in2] * Wd.p[l + 1][t] / rs;
        }
        __syncthreads();
        if (t < knext) {
#pragma unroll
            for (int w = 0; w < 16; ++w) sCP[in2 * MS + w] = Q[w];
            srsO[in2] = (float)(knext - pc2);
            svC[t] = su2_;
            svO[in2] = su2_;
        } else if (t < 512) {
            svC[t] = 0.f;
        }
        __syncthreads();
    }
}

extern "C" void kernel_launch(void* const* d_in, const int* in_sizes, int n_in,
                              void* d_out, int out_size, void* d_ws, size_t ws_size,
                              hipStream_t stream) {
    const float* g = (const float*)d_in[0];
    const float* h = (const float*)d_in[1];
    const float* W_top = (const float*)d_in[2];
    const float* b_top = (const float*)d_in[3];
    P4 Wp, bp, Wd, bd;
    for (int i = 0; i < 4; ++i) {
        Wp.p[i] = (const float*)d_in[4 + 4 * i];
        bp.p[i] = (const float*)d_in[5 + 4 * i];
        Wd.p[i] = (const float*)d_in[6 + 4 * i];
        bd.p[i] = (const float*)d_in[7 + 4 * i];
    }
    float* out = (float*)d_out;

    unsigned* wsu = (unsigned*)d_ws;
    float* V = (float*)(wsu + 0);
    float* SHg = (float*)(wsu + 512);
    float* Zg = (float*)(wsu + 1024);
    int* IDXA = (int*)(wsu + 1536);
    float* HSo = (float*)(wsu + 2048);
    unsigned* CPP = wsu + 2560;
    unsigned* MA = wsu + 10560;

    k_dot<<<500, 1024, 0, stream>>>(h, W_top, g, V, MA);
    k_row<<<125, 256, 0, stream>>>(MA, V, b_top, nullptr, SHg, out, 0);
    k_row<<<125, 256, 0, stream>>>(MA, SHg, Wp.p[0], bp.p[0], Zg, nullptr, 1);
    k_rh<<<125, 256, 0, stream>>>(MA, SHg, Zg, IDXA, HSo, CPP);
    k_fin<<<1, 1024, 0, stream>>>(IDXA, CPP, HSo, Wp, bp, Wd, bd, out);
}